// Round 7
// baseline (538.857 us; speedup 1.0000x reference)
//
#include <hip/hip_runtime.h>
#include <math.h>

#define NB 16
#define NT 363
#define NC 180
#define SZF 557568   // NB*96*NT
#define NROW 5808    // NB*NT

__device__ __forceinline__ float gelu_f(float x) {
  return 0.5f * x * (1.0f + erff(x * 0.7071067811865475244f));
}

// ================= quantum gate primitives (v2 layout — measured best) =================
// k_quantum: 16 amps/lane. local j = state bits [3:0];
// lane bits [3:0] = state bits [7:4]; lane bits [5:4] = row-in-wave g.
// wire w acts on state bit p = 7-w.
// p<=3 local; p=4 lane^1 (DPP); p=5 lane^2 (DPP); p=6 lane^4 (DS); p=7 lane^8 (DS).

template<int CTRL>
__device__ __forceinline__ float dppf(float x) {
  return __int_as_float(__builtin_amdgcn_update_dpp(
      0, __float_as_int(x), CTRL, 0xF, 0xF, true));
}

template<int LB>
__device__ __forceinline__ float lx(float x) {
  if constexpr (LB == 0) return dppf<0xB1>(x);        // quad_perm xor 1
  else if constexpr (LB == 1) return dppf<0x4E>(x);   // quad_perm xor 2
  else if constexpr (LB == 2) return __shfl_xor(x, 4);
  else return __shfl_xor(x, 8);
}

template<int P>
__device__ __forceinline__ void ry_local(float* re, float* im, float c, float s) {
#pragma unroll
  for (int j = 0; j < 16; ++j) {
    if ((j & (1 << P)) == 0) {
      int k = j | (1 << P);
      float r0 = re[j], i0 = im[j], r1 = re[k], i1 = im[k];
      re[j] = fmaf(c, r0, -s * r1); im[j] = fmaf(c, i0, -s * i1);
      re[k] = fmaf(s, r0,  c * r1); im[k] = fmaf(s, i0,  c * i1);
    }
  }
}

template<int LB>
__device__ __forceinline__ void ry_lane(float* re, float* im, float c, float s, int lane) {
  float sg = (lane & (1 << LB)) ? s : -s;
#pragma unroll
  for (int j = 0; j < 16; ++j) {
    float br = lx<LB>(re[j]);
    float bi = lx<LB>(im[j]);
    re[j] = fmaf(c, re[j], sg * br);
    im[j] = fmaf(c, im[j], sg * bi);
  }
}

template<int Q, int P>  // control local bit Q, target local bit P
__device__ __forceinline__ void crx_ll(float* re, float* im, float cs, float sn) {
#pragma unroll
  for (int j = 0; j < 16; ++j) {
    if ((j & (1 << Q)) && !(j & (1 << P))) {
      int k = j | (1 << P);
      float r0 = re[j], i0 = im[j], r1 = re[k], i1 = im[k];
      re[j] = fmaf(cs, r0,  sn * i1); im[j] = fmaf(cs, i0, -sn * r1);
      re[k] = fmaf(cs, r1,  sn * i0); im[k] = fmaf(cs, i1, -sn * r0);
    }
  }
}

template<int LBQ, int P>  // control lane bit LBQ, target local bit P
__device__ __forceinline__ void crx_nl(float* re, float* im, float cs, float sn, int lane) {
  if (lane & (1 << LBQ)) {
#pragma unroll
    for (int j = 0; j < 16; ++j) {
      if ((j & (1 << P)) == 0) {
        int k = j | (1 << P);
        float r0 = re[j], i0 = im[j], r1 = re[k], i1 = im[k];
        re[j] = fmaf(cs, r0,  sn * i1); im[j] = fmaf(cs, i0, -sn * r1);
        re[k] = fmaf(cs, r1,  sn * i0); im[k] = fmaf(cs, i1, -sn * r0);
      }
    }
  }
}

template<int Q, int LBP>  // control local bit Q, target lane bit LBP
__device__ __forceinline__ void crx_ln(float* re, float* im, float cs, float sn) {
#pragma unroll
  for (int j = 0; j < 16; ++j) {
    if (j & (1 << Q)) {
      float br = lx<LBP>(re[j]);
      float bi = lx<LBP>(im[j]);
      re[j] = fmaf(cs, re[j],  sn * bi);
      im[j] = fmaf(cs, im[j], -sn * br);
    }
  }
}

template<int LBQ, int LBP>  // control lane bit LBQ, target lane bit LBP
__device__ __forceinline__ void crx_nn(float* re, float* im, float cs, float sn, int lane) {
  bool ctl = (lane & (1 << LBQ)) != 0;
#pragma unroll
  for (int j = 0; j < 16; ++j) {
    float br = lx<LBP>(re[j]);
    float bi = lx<LBP>(im[j]);
    if (ctl) {
      re[j] = fmaf(cs, re[j],  sn * bi);
      im[j] = fmaf(cs, im[j], -sn * br);
    }
  }
}

// one reference "layer" = RY ring, CRX(q,q+1) ring, RY ring, CRX(q,q-1) ring
__device__ __forceinline__ void qlayer(float* re, float* im,
                                       const float2* ang, int lane) {
  float2 a;
  a = ang[0];  ry_lane<3>(re, im, a.x, a.y, lane);
  a = ang[1];  ry_lane<2>(re, im, a.x, a.y, lane);
  a = ang[2];  ry_lane<1>(re, im, a.x, a.y, lane);
  a = ang[3];  ry_lane<0>(re, im, a.x, a.y, lane);
  a = ang[4];  ry_local<3>(re, im, a.x, a.y);
  a = ang[5];  ry_local<2>(re, im, a.x, a.y);
  a = ang[6];  ry_local<1>(re, im, a.x, a.y);
  a = ang[7];  ry_local<0>(re, im, a.x, a.y);
  a = ang[8];  crx_nn<3, 2>(re, im, a.x, a.y, lane);
  a = ang[9];  crx_nn<2, 1>(re, im, a.x, a.y, lane);
  a = ang[10]; crx_nn<1, 0>(re, im, a.x, a.y, lane);
  a = ang[11]; crx_nl<0, 3>(re, im, a.x, a.y, lane);
  a = ang[12]; crx_ll<3, 2>(re, im, a.x, a.y);
  a = ang[13]; crx_ll<2, 1>(re, im, a.x, a.y);
  a = ang[14]; crx_ll<1, 0>(re, im, a.x, a.y);
  a = ang[15]; crx_ln<0, 3>(re, im, a.x, a.y);
  a = ang[16]; ry_lane<3>(re, im, a.x, a.y, lane);
  a = ang[17]; ry_lane<2>(re, im, a.x, a.y, lane);
  a = ang[18]; ry_lane<1>(re, im, a.x, a.y, lane);
  a = ang[19]; ry_lane<0>(re, im, a.x, a.y, lane);
  a = ang[20]; ry_local<3>(re, im, a.x, a.y);
  a = ang[21]; ry_local<2>(re, im, a.x, a.y);
  a = ang[22]; ry_local<1>(re, im, a.x, a.y);
  a = ang[23]; ry_local<0>(re, im, a.x, a.y);
  a = ang[24]; crx_nl<3, 0>(re, im, a.x, a.y, lane);
  a = ang[25]; crx_nn<2, 3>(re, im, a.x, a.y, lane);
  a = ang[26]; crx_nn<1, 2>(re, im, a.x, a.y, lane);
  a = ang[27]; crx_nn<0, 1>(re, im, a.x, a.y, lane);
  a = ang[28]; crx_ln<3, 0>(re, im, a.x, a.y);
  a = ang[29]; crx_ll<2, 3>(re, im, a.x, a.y);
  a = ang[30]; crx_ll<1, 2>(re, im, a.x, a.y);
  a = ang[31]; crx_ll<0, 1>(re, im, a.x, a.y);
}

// --- v1 layout helpers (4 amps/lane) for the tail qff step ---
template<int P>
__device__ __forceinline__ void ryg(float* re, float* im, float c, float s, int lane) {
  if constexpr (P >= 2) {
    constexpr int mask = 1 << (P - 2);
    float sg = ((lane >> (P - 2)) & 1) ? s : -s;
#pragma unroll
    for (int j = 0; j < 4; ++j) {
      float br = __shfl_xor(re[j], mask);
      float bi = __shfl_xor(im[j], mask);
      re[j] = fmaf(c, re[j], sg * br);
      im[j] = fmaf(c, im[j], sg * bi);
    }
  } else {
#pragma unroll
    for (int k = 0; k < 2; ++k) {
      const int a = (P == 0) ? 2 * k : k;
      const int b = (P == 0) ? a + 1 : a + 2;
      float r0 = re[a], i0 = im[a], r1 = re[b], i1 = im[b];
      re[a] = fmaf(c, r0, -s * r1); im[a] = fmaf(c, i0, -s * i1);
      re[b] = fmaf(s, r0,  c * r1); im[b] = fmaf(s, i0,  c * i1);
    }
  }
}

template<int PC, int PT>
__device__ __forceinline__ void crxg(float* re, float* im, float cs, float sn, int lane) {
  if constexpr (PT >= 2) {
    constexpr int mask = 1 << (PT - 2);
#pragma unroll
    for (int j = 0; j < 4; ++j) {
      float br = __shfl_xor(re[j], mask);
      float bi = __shfl_xor(im[j], mask);
      bool ctrl;
      if constexpr (PC >= 2) ctrl = ((lane >> (PC - 2)) & 1) != 0;
      else                   ctrl = ((j >> PC) & 1) != 0;
      if (ctrl) {
        float nr = fmaf(cs, re[j],  sn * bi);
        float ni = fmaf(cs, im[j], -sn * br);
        re[j] = nr; im[j] = ni;
      }
    }
  } else {
#pragma unroll
    for (int k = 0; k < 2; ++k) {
      const int a = (PT == 0) ? 2 * k : k;
      const int b = (PT == 0) ? a + 1 : a + 2;
      bool ctrl;
      if constexpr (PC >= 2) ctrl = ((lane >> (PC - 2)) & 1) != 0;
      else                   ctrl = ((a >> PC) & 1) != 0;
      if (ctrl) {
        float r0 = re[a], i0 = im[a], r1 = re[b], i1 = im[b];
        re[a] = fmaf(cs, r0,  sn * i1); im[a] = fmaf(cs, i0, -sn * r1);
        re[b] = fmaf(cs, r1,  sn * i0); im[b] = fmaf(cs, i1, -sn * r0);
      }
    }
  }
}

__device__ __forceinline__ void sim14_layer(float* re, float* im,
                                            const float* Cr, const float* Sr, int lane) {
#define ARY1(q, pi) ryg<7-(q)>(re, im, Cr[pi], Sr[pi], lane)
#define ACX1(cq, tq, pi) crxg<7-(cq), 7-(tq)>(re, im, Cr[pi], Sr[pi], lane)
  ARY1(0,0); ARY1(1,1); ARY1(2,2); ARY1(3,3); ARY1(4,4); ARY1(5,5); ARY1(6,6); ARY1(7,7);
  ACX1(0,1,8); ACX1(1,2,9); ACX1(2,3,10); ACX1(3,4,11); ACX1(4,5,12); ACX1(5,6,13); ACX1(6,7,14); ACX1(7,0,15);
  ARY1(0,16); ARY1(1,17); ARY1(2,18); ARY1(3,19); ARY1(4,20); ARY1(5,21); ARY1(6,22); ARY1(7,23);
  ACX1(0,7,24); ACX1(1,0,25); ACX1(2,1,26); ACX1(3,2,27); ACX1(4,3,28); ACX1(5,4,29); ACX1(6,5,30); ACX1(7,6,31);
#undef ARY1
#undef ACX1
}

// ---------------- K1: fused embed + depthwise conv (all 3 branches) ----------------
__global__ __launch_bounds__(256) void k_emdw(const float* __restrict__ x,
    const float* __restrict__ nw, const float* __restrict__ nb,
    const float* __restrict__ wa, const float* __restrict__ ba,
    const float* __restrict__ wb, const float* __restrict__ bb,
    const float* __restrict__ wc, const float* __restrict__ bc,
    float* __restrict__ y1base) {
  int b = blockIdx.x, kg = blockIdx.y, tid = threadIdx.x;
  __shared__ float xs[NT * 15];
  __shared__ float nwL[120], nbL[8];
  __shared__ float hrow[8][368];
  __shared__ float wL[3][8][8];
  __shared__ float bL[3][8];
  for (int i = tid; i < 120; i += 256) nwL[i] = nw[kg * 120 + i];
  for (int i = tid; i < 8; i += 256) nbL[i] = nb[kg * 8 + i];
  for (int i = tid; i < 168; i += 256) {
    int z = i / 56, r = i % 56, d = r / 7, k = r % 7;
    const float* w = (z == 0) ? wa : ((z == 1) ? wb : wc);
    wL[z][d][k] = w[(kg * 8 + d) * 7 + k];
  }
  for (int i = tid; i < 24; i += 256) {
    int z = i / 8, d = i % 8;
    const float* bias = (z == 0) ? ba : ((z == 1) ? bb : bc);
    bL[z][d] = bias[kg * 8 + d];
  }
  for (int i = tid; i < NT * 15; i += 256) {
    int t = i / 15, u = i % 15;
    xs[i] = x[((size_t)b * NT + t) * NC + kg * 15 + u];
  }
  __syncthreads();
  for (int i = tid; i < 8 * NT; i += 256) {
    int t = i % NT, d = i / NT;
    float acc2 = nbL[d];
#pragma unroll
    for (int u = 0; u < 15; ++u) acc2 = fmaf(xs[t * 15 + u], nwL[u * 8 + d], acc2);
    hrow[d][t] = gelu_f(acc2);
  }
  __syncthreads();
  for (int i = tid; i < 8 * NT; i += 256) {
    int t = i % NT, d = i / NT;
    int c = kg * 8 + d;
    float a0 = bL[0][d], a1 = bL[1][d], a2 = bL[2][d];
#pragma unroll
    for (int k = 0; k < 7; ++k) {
      int i1 = t + (k - 3);
      int i4 = t + (k - 3) * 4;
      int i16 = t + (k - 3) * 16;
      if (i1 >= 0 && i1 < NT)  a0 = fmaf(hrow[d][i1],  wL[0][d][k], a0);
      if (i4 >= 0 && i4 < NT)  a1 = fmaf(hrow[d][i4],  wL[1][d][k], a1);
      if (i16 >= 0 && i16 < NT) a2 = fmaf(hrow[d][i16], wL[2][d][k], a2);
    }
    size_t base = ((size_t)b * 96 + c) * NT + t;
    y1base[base] = a0;
    y1base[SZF + base] = a1;
    y1base[2 * SZF + base] = a2;
  }
}

// ---------------- K2: pointwise 96x96, branch-batched; float4 weight reads ----------------
__global__ __launch_bounds__(256) void k_pw(const float* __restrict__ y1base,
    const float* __restrict__ wA, const float* __restrict__ wB, const float* __restrict__ wC,
    const float* __restrict__ bA, const float* __restrict__ bB, const float* __restrict__ bC,
    float* __restrict__ y2base) {
  int b = blockIdx.x, tile = blockIdx.y, z = blockIdx.z, tid = threadIdx.x;
  const float* pw_w = (z == 0) ? wA : ((z == 1) ? wB : wC);
  const float* pw_b = (z == 0) ? bA : ((z == 1) ? bB : bC);
  const float* y1 = y1base + (size_t)z * SZF;
  float* y2 = y2base + (size_t)z * SZF;
  int t0 = tile * 64;
  __shared__ float y1t[96 * 64];
  __shared__ float pwL[96 * 100];  // pad 100: breaks bank aliasing AND keeps rows 16B-aligned
  for (int i = tid; i < 96 * 96; i += 256) {
    int o = i / 96, cc = i % 96;
    pwL[o * 100 + cc] = pw_w[i];
  }
  for (int i = tid; i < 96 * 64; i += 256) {
    int cc = i >> 6, t = i & 63;
    int tt = t0 + t;
    y1t[i] = (tt < NT) ? y1[(b * 96 + cc) * NT + tt] : 0.0f;
  }
  __syncthreads();
  int o16 = tid >> 4, t4 = (tid & 15) * 4;
  for (int pass = 0; pass < 6; ++pass) {
    int o = pass * 16 + o16;
    float bias = pw_b[o];
    float a0 = bias, a1 = bias, a2 = bias, a3 = bias;
    const float* wrow = &pwL[o * 100];
    for (int cc4 = 0; cc4 < 24; ++cc4) {
      const float4 w4 = *reinterpret_cast<const float4*>(&wrow[cc4 * 4]);
#pragma unroll
      for (int e = 0; e < 4; ++e) {
        int cc = cc4 * 4 + e;
        const float4 vy = *reinterpret_cast<const float4*>(&y1t[cc * 64 + t4]);
        float w = (e == 0) ? w4.x : (e == 1) ? w4.y : (e == 2) ? w4.z : w4.w;
        a0 = fmaf(w, vy.x, a0); a1 = fmaf(w, vy.y, a1);
        a2 = fmaf(w, vy.z, a2); a3 = fmaf(w, vy.w, a3);
      }
    }
    int base = (b * 96 + o) * NT;
    int t = t0 + t4;
    if (t + 3 < NT) {
      y2[base + t] = a0; y2[base + t + 1] = a1; y2[base + t + 2] = a2; y2[base + t + 3] = a3;
    } else {
      if (t < NT) y2[base + t] = a0;
      if (t + 1 < NT) y2[base + t + 1] = a1;
      if (t + 2 < NT) y2[base + t + 2] = a2;
      if (t + 3 < NT) y2[base + t + 3] = a3;
    }
  }
}

// ---------------- K3: fused groupnorm stats + apply + gelu -> cat ----------------
__global__ __launch_bounds__(256) void k_gn(const float* __restrict__ y2base,
    const float* __restrict__ gA, const float* __restrict__ gB, const float* __restrict__ gC,
    const float* __restrict__ bA, const float* __restrict__ bB, const float* __restrict__ bC,
    float* __restrict__ cat) {
  int b = blockIdx.x, tile = blockIdx.y, z = blockIdx.z, tid = threadIdx.x;
  const float* gng = (z == 0) ? gA : ((z == 1) ? gB : gC);
  const float* gnb = (z == 0) ? bA : ((z == 1) ? bB : bC);
  const float* y2 = y2base + (size_t)z * SZF + (size_t)b * 96 * NT;
  __shared__ float redS[256], redQ[256];
  __shared__ float muL[8], rsL[8];
  __shared__ float yL[96 * 65];
  // Phase A: per-group stats over the full (b,z) slab (single pass sum/sumsq)
  for (int g = 0; g < 8; ++g) {
    const float* gb = y2 + g * 12 * NT;
    float s = 0, q = 0;
    for (int i = tid; i < 12 * NT; i += 256) { float v = gb[i]; s += v; q = fmaf(v, v, q); }
    redS[tid] = s; redQ[tid] = q;
    __syncthreads();
    for (int st = 128; st > 0; st >>= 1) {
      if (tid < st) { redS[tid] += redS[tid + st]; redQ[tid] += redQ[tid + st]; }
      __syncthreads();
    }
    if (tid == 0) {
      float mu = redS[0] / 4356.0f;
      float var = redQ[0] / 4356.0f - mu * mu;
      muL[g] = mu;
      rsL[g] = rsqrtf(fmaxf(var, 0.0f) + 1e-5f);
    }
    __syncthreads();
  }
  // Phase B: apply + gelu for this tile (transpose via LDS)
  int t0 = tile * 64;
  for (int i = tid; i < 96 * 64; i += 256) {
    int cc = i >> 6, t = i & 63;
    int tt = t0 + t;
    yL[cc * 65 + t] = (tt < NT) ? y2[cc * NT + tt] : 0.0f;
  }
  __syncthreads();
  for (int i = tid; i < 64 * 96; i += 256) {
    int tt = i / 96, cc = i % 96;
    int t = t0 + tt;
    if (t < NT) {
      int g = cc / 12;
      float v = (yL[cc * 65 + tt] - muL[g]) * rsL[g] * gng[cc] + gnb[cc];
      cat[((size_t)b * NT + t) * 288 + z * 96 + cc] = gelu_f(v);
    }
  }
}

// ---------------- K4: merge GEMM + LN + GELU + qproj + sigmoid -> angles;
//                  blocks 726..741 run the correlation path -> fusedG ----------------
struct CorrSM { float mu[180]; float inv[180]; float S[NT * 12]; float fcv[78]; };
struct MergeSM {
  float catL[8][288];
  float vL[8][132];
  float hL[8][132];
  float muS[8], rsS[8];
};
union MCSM { MergeSM m; CorrSM c; };

__global__ __launch_bounds__(256) void k_merge(const float* __restrict__ cat,
    const float* __restrict__ mw, const float* __restrict__ mb,
    const float* __restrict__ lng, const float* __restrict__ lnb,
    const float* __restrict__ qw, const float* __restrict__ qb,
    float2* __restrict__ angG,
    const float* __restrict__ x,
    const float* __restrict__ fcw, const float* __restrict__ fcb,
    float* __restrict__ fusedG) {
  __shared__ MCSM sm;
  int tid = threadIdx.x;
  if (blockIdx.x < 726) {
    int blk = blockIdx.x;
    for (int i = tid; i < 8 * 288; i += 256) {
      int r = i / 288, k = i % 288;
      sm.m.catL[r][k] = cat[((size_t)blk * 8 + r) * 288 + k];
    }
    __syncthreads();
    int jj = tid & 127, rg = tid >> 7;
    float bias = mb[jj];
    float acc[4] = {bias, bias, bias, bias};
    {
      const float4* c0 = reinterpret_cast<const float4*>(&sm.m.catL[rg * 4 + 0][0]);
      const float4* c1 = reinterpret_cast<const float4*>(&sm.m.catL[rg * 4 + 1][0]);
      const float4* c2 = reinterpret_cast<const float4*>(&sm.m.catL[rg * 4 + 2][0]);
      const float4* c3 = reinterpret_cast<const float4*>(&sm.m.catL[rg * 4 + 3][0]);
      for (int k4 = 0; k4 < 72; ++k4) {
        float w0 = mw[(k4 * 4 + 0) * 128 + jj];
        float w1 = mw[(k4 * 4 + 1) * 128 + jj];
        float w2 = mw[(k4 * 4 + 2) * 128 + jj];
        float w3 = mw[(k4 * 4 + 3) * 128 + jj];
        float4 v0 = c0[k4], v1 = c1[k4], v2 = c2[k4], v3 = c3[k4];
        acc[0] = fmaf(v0.x, w0, fmaf(v0.y, w1, fmaf(v0.z, w2, fmaf(v0.w, w3, acc[0]))));
        acc[1] = fmaf(v1.x, w0, fmaf(v1.y, w1, fmaf(v1.z, w2, fmaf(v1.w, w3, acc[1]))));
        acc[2] = fmaf(v2.x, w0, fmaf(v2.y, w1, fmaf(v2.z, w2, fmaf(v2.w, w3, acc[2]))));
        acc[3] = fmaf(v3.x, w0, fmaf(v3.y, w1, fmaf(v3.z, w2, fmaf(v3.w, w3, acc[3]))));
      }
    }
#pragma unroll
    for (int r = 0; r < 4; ++r) sm.m.vL[rg * 4 + r][jj] = acc[r];
    __syncthreads();
    if (tid < 8) {
      float s = 0;
      for (int k = 0; k < 128; ++k) s += sm.m.vL[tid][k];
      float mu = s / 128.0f;
      float q = 0;
      for (int k = 0; k < 128; ++k) { float d = sm.m.vL[tid][k] - mu; q = fmaf(d, d, q); }
      sm.m.muS[tid] = mu;
      sm.m.rsS[tid] = rsqrtf(q / 128.0f + 1e-5f);
    }
    __syncthreads();
    float g = lng[jj], bb2 = lnb[jj];
#pragma unroll
    for (int r = 0; r < 4; ++r) {
      int row = rg * 4 + r;
      float h = (acc[r] - sm.m.muS[row]) * sm.m.rsS[row] * g + bb2;
      sm.m.hL[row][jj] = gelu_f(h);
    }
    __syncthreads();
    int o = tid & 63;
    int r0 = (tid >> 6) * 2;
    for (int rr = 0; rr < 2; ++rr) {
      int row = r0 + rr;
      float u = qb[o];
      const float4* h4 = reinterpret_cast<const float4*>(&sm.m.hL[row][0]);
      for (int k4 = 0; k4 < 32; ++k4) {
        float4 hv = h4[k4];
        u = fmaf(hv.x, qw[(k4 * 4 + 0) * 64 + o],
            fmaf(hv.y, qw[(k4 * 4 + 1) * 64 + o],
            fmaf(hv.z, qw[(k4 * 4 + 2) * 64 + o],
            fmaf(hv.w, qw[(k4 * 4 + 3) * 64 + o], u))));
      }
      float tp = 6.2831853071795864769f / (1.0f + expf(-u));
      float hf = tp * 0.5f;
      int grow = blk * 8 + row;
      angG[(size_t)grow * 64 + o] = make_float2(cosf(hf), sinf(hf));
    }
  } else {
    int b = blockIdx.x - 726;
    if (tid < 180) {
      float s = 0;
      const float* px = x + (size_t)b * NT * NC + tid;
      for (int t = 0; t < NT; ++t) s += px[t * NC];
      float mu = s / 363.0f;
      float q = 0;
      for (int t = 0; t < NT; ++t) { float d = px[t * NC] - mu; q = fmaf(d, d, q); }
      float sd = sqrtf(q / 362.0f);
      sd = fmaxf(sd, 1e-8f);
      sm.c.mu[tid] = mu; sm.c.inv[tid] = 1.0f / sd;
    }
    __syncthreads();
    for (int t = tid; t < NT; t += 256) {
      const float* px = x + (size_t)(b * NT + t) * NC;
#pragma unroll
      for (int i = 0; i < 12; ++i) {
        float s = 0;
#pragma unroll
        for (int u = 0; u < 15; ++u) {
          int cidx = i * 15 + u;
          s += (px[cidx] - sm.c.mu[cidx]) * sm.c.inv[cidx];
        }
        sm.c.S[t * 12 + i] = s;
      }
    }
    __syncthreads();
    if (tid < 78) {
      int i = 0, rem = tid;
      while (rem >= 12 - i) { rem -= 12 - i; ++i; }
      int j = i + rem;
      float acc = 0;
      for (int t = 0; t < NT; ++t) acc = fmaf(sm.c.S[t * 12 + i], sm.c.S[t * 12 + j], acc);
      sm.c.fcv[tid] = acc * (1.0f / (225.0f * 362.0f));
    }
    __syncthreads();
    if (tid < 64) {
      float v = fcb[tid];
#pragma unroll
      for (int k = 0; k < 78; ++k) v = fmaf(sm.c.fcv[k], fcw[k * 64 + tid], v);
      fusedG[b * 192 + 128 + tid] = gelu_f(v);
    }
  }
}

// ---------------- K5: quantum ansatz (v2: 16 amps/lane, 4 rows/wave, Horner) ----------------
__global__ __launch_bounds__(64) void k_quantum(const float2* __restrict__ angG,
                                                const float* __restrict__ pc4,
                                                float* __restrict__ accG) {
  const int lane = threadIdx.x;
  const int g = lane >> 4;
  const int ll = lane & 15;
  const int row0 = blockIdx.x * 4;
  __shared__ float2 angL[4][66];  // pad 66 so the 4 subgroup bases hit distinct banks
#pragma unroll
  for (int q = 0; q < 4; ++q)
    angL[q][lane] = angG[(size_t)(row0 + q) * 64 + lane];
  __syncthreads();
  float p0 = pc4[0], p1 = pc4[1], p2 = pc4[2], p3 = pc4[3];
  float re[16], im[16];
#pragma unroll
  for (int j = 0; j < 16; ++j) { re[j] = 0.0f; im[j] = 0.0f; }
  // Horner: acc = p0 + U(p1 + U(p2 + U*p3)) |0>
  if (ll == 0) re[0] = p3;
  const float2* ang = &angL[g][0];
  for (int rep = 0; rep < 3; ++rep) {
    qlayer(re, im, ang, lane);
    qlayer(re, im, ang + 32, lane);
    float pc = (rep == 0) ? p2 : (rep == 1) ? p1 : p0;
    if (ll == 0) re[0] += pc;
  }
  int row = row0 + g;
  float4* dst = reinterpret_cast<float4*>(accG + ((size_t)row * 256 + ll * 16) * 2);
#pragma unroll
  for (int h = 0; h < 8; ++h)
    dst[h] = make_float4(re[2 * h], im[2 * h], re[2 * h + 1], im[2 * h + 1]);
}

// ---------------- K6: tail — mix + qff + pauli + qout + final MLP -> out ----------------
__global__ __launch_bounds__(256) void k_tail(const float* __restrict__ accG,
    const float* __restrict__ mr, const float* __restrict__ mi,
    const float* __restrict__ qff,
    const float* __restrict__ qout_w, const float* __restrict__ qout_b,
    const float* __restrict__ fusedG,
    const float* __restrict__ w1, const float* __restrict__ b1,
    const float* __restrict__ lng, const float* __restrict__ lnb,
    const float* __restrict__ w2, const float* __restrict__ b2,
    float* __restrict__ out) {
  int b = blockIdx.x, tid = threadIdx.x;
  __shared__ float psiL[256][2];
  __shared__ float red[256];
  __shared__ float qcL[32], qsL[32], exps[24];
  __shared__ float tL[128], cL[64], hL[128];
  {
    const float2* av = reinterpret_cast<const float2*>(accG) + (size_t)b * NT * 256 + tid;
    float sr = 0, si = 0;
#pragma unroll 3
    for (int t = 0; t < NT; ++t) {
      float2 a = av[(size_t)t * 256];
      float m_r = mr[t], m_i = mi[t];
      sr = fmaf(m_r, a.x, fmaf(-m_i, a.y, sr));
      si = fmaf(m_r, a.y, fmaf(m_i, a.x, si));
    }
    psiL[tid][0] = sr; psiL[tid][1] = si;
    red[tid] = sr * sr + si * si;
  }
  if (tid < 32) { float h = qff[tid] * 0.5f; qcL[tid] = cosf(h); qsL[tid] = sinf(h); }
  __syncthreads();
  for (int s2 = 128; s2 > 0; s2 >>= 1) { if (tid < s2) red[tid] += red[tid + s2]; __syncthreads(); }
  float inv = 1.0f / (sqrtf(red[0]) + 1e-9f);
  __syncthreads();
  if (tid < 64) {
    int lane = tid;
    float re[4], im[4];
#pragma unroll
    for (int j = 0; j < 4; ++j) {
      re[j] = psiL[lane * 4 + j][0] * inv;
      im[j] = psiL[lane * 4 + j][1] * inv;
    }
    sim14_layer(re, im, qcL, qsL, lane);
#pragma unroll
    for (int j = 0; j < 4; ++j) { psiL[lane * 4 + j][0] = re[j]; psiL[lane * 4 + j][1] = im[j]; }
  }
  __syncthreads();
  if (tid < 64) {
    int lane = tid;
    for (int w = 0; w < 8; ++w) {
      int p = 7 - w;
      float cr = 0, ci = 0, z = 0;
#pragma unroll
      for (int k = 0; k < 2; ++k) {
        int pr = lane + k * 64;
        int lowmask = (1 << p) - 1;
        int i0 = ((pr >> p) << (p + 1)) | (pr & lowmask);
        int i1 = i0 | (1 << p);
        float r0 = psiL[i0][0], I0 = psiL[i0][1], r1 = psiL[i1][0], I1 = psiL[i1][1];
        cr += r0 * r1 + I0 * I1;
        ci += r0 * I1 - I0 * r1;
        z += r0 * r0 + I0 * I0 - r1 * r1 - I1 * I1;
      }
      for (int off = 32; off > 0; off >>= 1) {
        cr += __shfl_down(cr, off);
        ci += __shfl_down(ci, off);
        z  += __shfl_down(z, off);
      }
      if (lane == 0) { exps[w] = 2.0f * cr; exps[8 + w] = 2.0f * ci; exps[16 + w] = z; }
    }
  }
  __syncthreads();
  if (tid < 128) {
    float v = qout_b[tid];
#pragma unroll
    for (int k = 0; k < 24; ++k) v = fmaf(exps[k], qout_w[k * 128 + tid], v);
    tL[tid] = v;
  } else if (tid < 192) {
    cL[tid - 128] = fusedG[b * 192 + 128 + (tid - 128)];
  }
  __syncthreads();
  float v = 0.0f;
  if (tid < 128) {
    v = b1[tid];
    for (int k = 0; k < 128; ++k) v = fmaf(tL[k], w1[k * 128 + tid], v);
    for (int k = 0; k < 64; ++k)  v = fmaf(cL[k], w1[(128 + k) * 128 + tid], v);
    red[tid] = v;
  }
  __syncthreads();
  for (int s = 64; s > 0; s >>= 1) { if (tid < s) red[tid] += red[tid + s]; __syncthreads(); }
  float mu = red[0] / 128.0f;
  __syncthreads();
  float dv = v - mu;
  if (tid < 128) red[tid] = dv * dv;
  __syncthreads();
  for (int s = 64; s > 0; s >>= 1) { if (tid < s) red[tid] += red[tid + s]; __syncthreads(); }
  float var = red[0] / 128.0f;
  if (tid < 128) hL[tid] = gelu_f(dv * rsqrtf(var + 1e-5f) * lng[tid] + lnb[tid]);
  __syncthreads();
  if (tid < 64) {
    float o = b2[tid];
    for (int k = 0; k < 128; ++k) o = fmaf(hL[k], w2[k * 64 + tid], o);
    out[b * 64 + tid] = o;
  }
}

extern "C" void kernel_launch(void* const* d_in, const int* in_sizes, int n_in,
                              void* d_out, int out_size, void* d_ws, size_t ws_size,
                              hipStream_t stream) {
  const float* x       = (const float*)d_in[0];
  const float* net_w   = (const float*)d_in[1];
  const float* net_b   = (const float*)d_in[2];
  const float* dwa_w   = (const float*)d_in[3];
  const float* dwa_b   = (const float*)d_in[4];
  const float* pwa_w   = (const float*)d_in[5];
  const float* pwa_b   = (const float*)d_in[6];
  const float* gna_g   = (const float*)d_in[7];
  const float* gna_b   = (const float*)d_in[8];
  const float* dwb_w   = (const float*)d_in[9];
  const float* dwb_b   = (const float*)d_in[10];
  const float* pwb_w   = (const float*)d_in[11];
  const float* pwb_b   = (const float*)d_in[12];
  const float* gnb_g   = (const float*)d_in[13];
  const float* gnb_b   = (const float*)d_in[14];
  const float* dwc_w   = (const float*)d_in[15];
  const float* dwc_b   = (const float*)d_in[16];
  const float* pwc_w   = (const float*)d_in[17];
  const float* pwc_b   = (const float*)d_in[18];
  const float* gnc_g   = (const float*)d_in[19];
  const float* gnc_b   = (const float*)d_in[20];
  const float* merge_w = (const float*)d_in[21];
  const float* merge_b = (const float*)d_in[22];
  const float* mlng    = (const float*)d_in[23];
  const float* mlnb    = (const float*)d_in[24];
  const float* qproj_w = (const float*)d_in[25];
  const float* qproj_b = (const float*)d_in[26];
  const float* poly    = (const float*)d_in[27];
  const float* qff     = (const float*)d_in[28];
  const float* mix_re  = (const float*)d_in[29];
  const float* mix_im  = (const float*)d_in[30];
  const float* qout_w  = (const float*)d_in[31];
  const float* qout_b  = (const float*)d_in[32];
  const float* fc_w    = (const float*)d_in[33];
  const float* fc_b    = (const float*)d_in[34];
  const float* fus1_w  = (const float*)d_in[35];
  const float* fus1_b  = (const float*)d_in[36];
  const float* flng    = (const float*)d_in[37];
  const float* flnb    = (const float*)d_in[38];
  const float* fus2_w  = (const float*)d_in[39];
  const float* fus2_b  = (const float*)d_in[40];
  float* out = (float*)d_out;

  // workspace layout (floats):
  //  [0, 3*SZF)        y1a/y1b/y1c   (dead after k_pw); cat aliases exactly
  //  [3*SZF, 6*SZF)    y2a/y2b/y2c   (dead after k_gn)
  //  acc aliases [0, 2,973,696) — written by k_quantum after k_merge read cat
  //  [6*SZF ...)       angG, fused
  float* W = (float*)d_ws;
  float* y1b_  = W;                                // 3*SZF
  float* cat   = W;                                // alias
  float* y2b_  = W + 3 * (size_t)SZF;
  float* acc   = W;                                // alias, len 2,973,696 (< 6*SZF)
  float2* angG = (float2*)(W + 6 * (size_t)SZF);   // 371,712 float2
  float* fused = W + 6 * (size_t)SZF + 743424;     // 3,072

  k_emdw<<<dim3(NB, 12), 256, 0, stream>>>(x, net_w, net_b,
      dwa_w, dwa_b, dwb_w, dwb_b, dwc_w, dwc_b, y1b_);
  k_pw<<<dim3(NB, 6, 3), 256, 0, stream>>>(y1b_, pwa_w, pwb_w, pwc_w, pwa_b, pwb_b, pwc_b, y2b_);
  k_gn<<<dim3(NB, 6, 3), 256, 0, stream>>>(y2b_,
      gna_g, gnb_g, gnc_g, gna_b, gnb_b, gnc_b, cat);
  k_merge<<<726 + NB, 256, 0, stream>>>(cat, merge_w, merge_b, mlng, mlnb,
      qproj_w, qproj_b, angG, x, fc_w, fc_b, fused);
  k_quantum<<<NROW / 4, 64, 0, stream>>>(angG, poly, acc);
  k_tail<<<NB, 256, 0, stream>>>(acc, mix_re, mix_im, qff, qout_w, qout_b, fused,
                                 fus1_w, fus1_b, flng, flnb, fus2_w, fus2_b, out);
}

// Round 8
// 398.556 us; speedup vs baseline: 1.3520x; 1.3520x over previous
//
#include <hip/hip_runtime.h>
#include <math.h>

#define NB 16
#define NT 363
#define NC 180
#define SZF 557568   // NB*96*NT
#define NROW 5808    // NB*NT

__device__ __forceinline__ float gelu_f(float x) {
  return 0.5f * x * (1.0f + erff(x * 0.7071067811865475244f));
}

// ================= quantum gate primitives (v2 layout — measured best) =================
// k_quantum: 16 amps/lane. local j = state bits [3:0];
// lane bits [3:0] = state bits [7:4]; lane bits [5:4] = row-in-wave g.
// wire w acts on state bit p = 7-w.
// p<=3 local; p=4 lane^1 (DPP); p=5 lane^2 (DPP); p=6 lane^4 (DS); p=7 lane^8 (DS).

template<int CTRL>
__device__ __forceinline__ float dppf(float x) {
  return __int_as_float(__builtin_amdgcn_update_dpp(
      0, __float_as_int(x), CTRL, 0xF, 0xF, true));
}

template<int LB>
__device__ __forceinline__ float lx(float x) {
  if constexpr (LB == 0) return dppf<0xB1>(x);        // quad_perm xor 1
  else if constexpr (LB == 1) return dppf<0x4E>(x);   // quad_perm xor 2
  else if constexpr (LB == 2) return __shfl_xor(x, 4);
  else return __shfl_xor(x, 8);
}

template<int P>
__device__ __forceinline__ void ry_local(float* re, float* im, float c, float s) {
#pragma unroll
  for (int j = 0; j < 16; ++j) {
    if ((j & (1 << P)) == 0) {
      int k = j | (1 << P);
      float r0 = re[j], i0 = im[j], r1 = re[k], i1 = im[k];
      re[j] = fmaf(c, r0, -s * r1); im[j] = fmaf(c, i0, -s * i1);
      re[k] = fmaf(s, r0,  c * r1); im[k] = fmaf(s, i0,  c * i1);
    }
  }
}

template<int LB>
__device__ __forceinline__ void ry_lane(float* re, float* im, float c, float s, int lane) {
  float sg = (lane & (1 << LB)) ? s : -s;
#pragma unroll
  for (int j = 0; j < 16; ++j) {
    float br = lx<LB>(re[j]);
    float bi = lx<LB>(im[j]);
    re[j] = fmaf(c, re[j], sg * br);
    im[j] = fmaf(c, im[j], sg * bi);
  }
}

template<int Q, int P>  // control local bit Q, target local bit P
__device__ __forceinline__ void crx_ll(float* re, float* im, float cs, float sn) {
#pragma unroll
  for (int j = 0; j < 16; ++j) {
    if ((j & (1 << Q)) && !(j & (1 << P))) {
      int k = j | (1 << P);
      float r0 = re[j], i0 = im[j], r1 = re[k], i1 = im[k];
      re[j] = fmaf(cs, r0,  sn * i1); im[j] = fmaf(cs, i0, -sn * r1);
      re[k] = fmaf(cs, r1,  sn * i0); im[k] = fmaf(cs, i1, -sn * r0);
    }
  }
}

template<int LBQ, int P>  // control lane bit LBQ, target local bit P
__device__ __forceinline__ void crx_nl(float* re, float* im, float cs, float sn, int lane) {
  if (lane & (1 << LBQ)) {
#pragma unroll
    for (int j = 0; j < 16; ++j) {
      if ((j & (1 << P)) == 0) {
        int k = j | (1 << P);
        float r0 = re[j], i0 = im[j], r1 = re[k], i1 = im[k];
        re[j] = fmaf(cs, r0,  sn * i1); im[j] = fmaf(cs, i0, -sn * r1);
        re[k] = fmaf(cs, r1,  sn * i0); im[k] = fmaf(cs, i1, -sn * r0);
      }
    }
  }
}

template<int Q, int LBP>  // control local bit Q, target lane bit LBP
__device__ __forceinline__ void crx_ln(float* re, float* im, float cs, float sn) {
#pragma unroll
  for (int j = 0; j < 16; ++j) {
    if (j & (1 << Q)) {
      float br = lx<LBP>(re[j]);
      float bi = lx<LBP>(im[j]);
      re[j] = fmaf(cs, re[j],  sn * bi);
      im[j] = fmaf(cs, im[j], -sn * br);
    }
  }
}

template<int LBQ, int LBP>  // control lane bit LBQ, target lane bit LBP
__device__ __forceinline__ void crx_nn(float* re, float* im, float cs, float sn, int lane) {
  bool ctl = (lane & (1 << LBQ)) != 0;
#pragma unroll
  for (int j = 0; j < 16; ++j) {
    float br = lx<LBP>(re[j]);
    float bi = lx<LBP>(im[j]);
    if (ctl) {
      re[j] = fmaf(cs, re[j],  sn * bi);
      im[j] = fmaf(cs, im[j], -sn * br);
    }
  }
}

// one reference "layer" = RY ring, CRX(q,q+1) ring, RY ring, CRX(q,q-1) ring
__device__ __forceinline__ void qlayer(float* re, float* im,
                                       const float2* ang, int lane) {
  float2 a;
  a = ang[0];  ry_lane<3>(re, im, a.x, a.y, lane);
  a = ang[1];  ry_lane<2>(re, im, a.x, a.y, lane);
  a = ang[2];  ry_lane<1>(re, im, a.x, a.y, lane);
  a = ang[3];  ry_lane<0>(re, im, a.x, a.y, lane);
  a = ang[4];  ry_local<3>(re, im, a.x, a.y);
  a = ang[5];  ry_local<2>(re, im, a.x, a.y);
  a = ang[6];  ry_local<1>(re, im, a.x, a.y);
  a = ang[7];  ry_local<0>(re, im, a.x, a.y);
  a = ang[8];  crx_nn<3, 2>(re, im, a.x, a.y, lane);
  a = ang[9];  crx_nn<2, 1>(re, im, a.x, a.y, lane);
  a = ang[10]; crx_nn<1, 0>(re, im, a.x, a.y, lane);
  a = ang[11]; crx_nl<0, 3>(re, im, a.x, a.y, lane);
  a = ang[12]; crx_ll<3, 2>(re, im, a.x, a.y);
  a = ang[13]; crx_ll<2, 1>(re, im, a.x, a.y);
  a = ang[14]; crx_ll<1, 0>(re, im, a.x, a.y);
  a = ang[15]; crx_ln<0, 3>(re, im, a.x, a.y);
  a = ang[16]; ry_lane<3>(re, im, a.x, a.y, lane);
  a = ang[17]; ry_lane<2>(re, im, a.x, a.y, lane);
  a = ang[18]; ry_lane<1>(re, im, a.x, a.y, lane);
  a = ang[19]; ry_lane<0>(re, im, a.x, a.y, lane);
  a = ang[20]; ry_local<3>(re, im, a.x, a.y);
  a = ang[21]; ry_local<2>(re, im, a.x, a.y);
  a = ang[22]; ry_local<1>(re, im, a.x, a.y);
  a = ang[23]; ry_local<0>(re, im, a.x, a.y);
  a = ang[24]; crx_nl<3, 0>(re, im, a.x, a.y, lane);
  a = ang[25]; crx_nn<2, 3>(re, im, a.x, a.y, lane);
  a = ang[26]; crx_nn<1, 2>(re, im, a.x, a.y, lane);
  a = ang[27]; crx_nn<0, 1>(re, im, a.x, a.y, lane);
  a = ang[28]; crx_ln<3, 0>(re, im, a.x, a.y);
  a = ang[29]; crx_ll<2, 3>(re, im, a.x, a.y);
  a = ang[30]; crx_ll<1, 2>(re, im, a.x, a.y);
  a = ang[31]; crx_ll<0, 1>(re, im, a.x, a.y);
}

// --- v1 layout helpers (4 amps/lane) for the tail qff step ---
template<int P>
__device__ __forceinline__ void ryg(float* re, float* im, float c, float s, int lane) {
  if constexpr (P >= 2) {
    constexpr int mask = 1 << (P - 2);
    float sg = ((lane >> (P - 2)) & 1) ? s : -s;
#pragma unroll
    for (int j = 0; j < 4; ++j) {
      float br = __shfl_xor(re[j], mask);
      float bi = __shfl_xor(im[j], mask);
      re[j] = fmaf(c, re[j], sg * br);
      im[j] = fmaf(c, im[j], sg * bi);
    }
  } else {
#pragma unroll
    for (int k = 0; k < 2; ++k) {
      const int a = (P == 0) ? 2 * k : k;
      const int b = (P == 0) ? a + 1 : a + 2;
      float r0 = re[a], i0 = im[a], r1 = re[b], i1 = im[b];
      re[a] = fmaf(c, r0, -s * r1); im[a] = fmaf(c, i0, -s * i1);
      re[b] = fmaf(s, r0,  c * r1); im[b] = fmaf(s, i0,  c * i1);
    }
  }
}

template<int PC, int PT>
__device__ __forceinline__ void crxg(float* re, float* im, float cs, float sn, int lane) {
  if constexpr (PT >= 2) {
    constexpr int mask = 1 << (PT - 2);
#pragma unroll
    for (int j = 0; j < 4; ++j) {
      float br = __shfl_xor(re[j], mask);
      float bi = __shfl_xor(im[j], mask);
      bool ctrl;
      if constexpr (PC >= 2) ctrl = ((lane >> (PC - 2)) & 1) != 0;
      else                   ctrl = ((j >> PC) & 1) != 0;
      if (ctrl) {
        float nr = fmaf(cs, re[j],  sn * bi);
        float ni = fmaf(cs, im[j], -sn * br);
        re[j] = nr; im[j] = ni;
      }
    }
  } else {
#pragma unroll
    for (int k = 0; k < 2; ++k) {
      const int a = (PT == 0) ? 2 * k : k;
      const int b = (PT == 0) ? a + 1 : a + 2;
      bool ctrl;
      if constexpr (PC >= 2) ctrl = ((lane >> (PC - 2)) & 1) != 0;
      else                   ctrl = ((a >> PC) & 1) != 0;
      if (ctrl) {
        float r0 = re[a], i0 = im[a], r1 = re[b], i1 = im[b];
        re[a] = fmaf(cs, r0,  sn * i1); im[a] = fmaf(cs, i0, -sn * r1);
        re[b] = fmaf(cs, r1,  sn * i0); im[b] = fmaf(cs, i1, -sn * r0);
      }
    }
  }
}

__device__ __forceinline__ void sim14_layer(float* re, float* im,
                                            const float* Cr, const float* Sr, int lane) {
#define ARY1(q, pi) ryg<7-(q)>(re, im, Cr[pi], Sr[pi], lane)
#define ACX1(cq, tq, pi) crxg<7-(cq), 7-(tq)>(re, im, Cr[pi], Sr[pi], lane)
  ARY1(0,0); ARY1(1,1); ARY1(2,2); ARY1(3,3); ARY1(4,4); ARY1(5,5); ARY1(6,6); ARY1(7,7);
  ACX1(0,1,8); ACX1(1,2,9); ACX1(2,3,10); ACX1(3,4,11); ACX1(4,5,12); ACX1(5,6,13); ACX1(6,7,14); ACX1(7,0,15);
  ARY1(0,16); ARY1(1,17); ARY1(2,18); ARY1(3,19); ARY1(4,20); ARY1(5,21); ARY1(6,22); ARY1(7,23);
  ACX1(0,7,24); ACX1(1,0,25); ACX1(2,1,26); ACX1(3,2,27); ACX1(4,3,28); ACX1(5,4,29); ACX1(6,5,30); ACX1(7,6,31);
#undef ARY1
#undef ACX1
}

// ---------------- K1: fused embed + depthwise conv (all 3 branches) ----------------
__global__ __launch_bounds__(256) void k_emdw(const float* __restrict__ x,
    const float* __restrict__ nw, const float* __restrict__ nb,
    const float* __restrict__ wa, const float* __restrict__ ba,
    const float* __restrict__ wb, const float* __restrict__ bb,
    const float* __restrict__ wc, const float* __restrict__ bc,
    float* __restrict__ y1base) {
  int b = blockIdx.x, kg = blockIdx.y, tid = threadIdx.x;
  __shared__ float xs[NT * 15];
  __shared__ float nwL[120], nbL[8];
  __shared__ float hrow[8][368];
  __shared__ float wL[3][8][8];
  __shared__ float bL[3][8];
  for (int i = tid; i < 120; i += 256) nwL[i] = nw[kg * 120 + i];
  for (int i = tid; i < 8; i += 256) nbL[i] = nb[kg * 8 + i];
  for (int i = tid; i < 168; i += 256) {
    int z = i / 56, r = i % 56, d = r / 7, k = r % 7;
    const float* w = (z == 0) ? wa : ((z == 1) ? wb : wc);
    wL[z][d][k] = w[(kg * 8 + d) * 7 + k];
  }
  for (int i = tid; i < 24; i += 256) {
    int z = i / 8, d = i % 8;
    const float* bias = (z == 0) ? ba : ((z == 1) ? bb : bc);
    bL[z][d] = bias[kg * 8 + d];
  }
  for (int i = tid; i < NT * 15; i += 256) {
    int t = i / 15, u = i % 15;
    xs[i] = x[((size_t)b * NT + t) * NC + kg * 15 + u];
  }
  __syncthreads();
  for (int i = tid; i < 8 * NT; i += 256) {
    int t = i % NT, d = i / NT;
    float acc2 = nbL[d];
#pragma unroll
    for (int u = 0; u < 15; ++u) acc2 = fmaf(xs[t * 15 + u], nwL[u * 8 + d], acc2);
    hrow[d][t] = gelu_f(acc2);
  }
  __syncthreads();
  for (int i = tid; i < 8 * NT; i += 256) {
    int t = i % NT, d = i / NT;
    int c = kg * 8 + d;
    float a0 = bL[0][d], a1 = bL[1][d], a2 = bL[2][d];
#pragma unroll
    for (int k = 0; k < 7; ++k) {
      int i1 = t + (k - 3);
      int i4 = t + (k - 3) * 4;
      int i16 = t + (k - 3) * 16;
      if (i1 >= 0 && i1 < NT)  a0 = fmaf(hrow[d][i1],  wL[0][d][k], a0);
      if (i4 >= 0 && i4 < NT)  a1 = fmaf(hrow[d][i4],  wL[1][d][k], a1);
      if (i16 >= 0 && i16 < NT) a2 = fmaf(hrow[d][i16], wL[2][d][k], a2);
    }
    size_t base = ((size_t)b * 96 + c) * NT + t;
    y1base[base] = a0;
    y1base[SZF + base] = a1;
    y1base[2 * SZF + base] = a2;
  }
}

// ---------------- K2: pointwise 96x96, branch-batched (R6 version — measured good) ----------------
__global__ __launch_bounds__(256) void k_pw(const float* __restrict__ y1base,
    const float* __restrict__ wA, const float* __restrict__ wB, const float* __restrict__ wC,
    const float* __restrict__ bA, const float* __restrict__ bB, const float* __restrict__ bC,
    float* __restrict__ y2base) {
  int b = blockIdx.x, tile = blockIdx.y, z = blockIdx.z, tid = threadIdx.x;
  const float* pw_w = (z == 0) ? wA : ((z == 1) ? wB : wC);
  const float* pw_b = (z == 0) ? bA : ((z == 1) ? bB : bC);
  const float* y1 = y1base + (size_t)z * SZF;
  float* y2 = y2base + (size_t)z * SZF;
  int t0 = tile * 64;
  __shared__ float y1t[96 * 64];
  __shared__ float pwL[96 * 97];  // pad 97 to break 96-stride bank aliasing
  for (int i = tid; i < 96 * 96; i += 256) {
    int o = i / 96, cc = i % 96;
    pwL[o * 97 + cc] = pw_w[i];
  }
  for (int i = tid; i < 96 * 64; i += 256) {
    int cc = i >> 6, t = i & 63;
    int tt = t0 + t;
    y1t[i] = (tt < NT) ? y1[(b * 96 + cc) * NT + tt] : 0.0f;
  }
  __syncthreads();
  int o16 = tid >> 4, t4 = (tid & 15) * 4;
  for (int pass = 0; pass < 6; ++pass) {
    int o = pass * 16 + o16;
    float bias = pw_b[o];
    float a0 = bias, a1 = bias, a2 = bias, a3 = bias;
    const float* wrow = &pwL[o * 97];
#pragma unroll 4
    for (int cc = 0; cc < 96; ++cc) {
      const float4 vy = *reinterpret_cast<const float4*>(&y1t[cc * 64 + t4]);
      float w = wrow[cc];
      a0 = fmaf(w, vy.x, a0); a1 = fmaf(w, vy.y, a1);
      a2 = fmaf(w, vy.z, a2); a3 = fmaf(w, vy.w, a3);
    }
    int base = (b * 96 + o) * NT;
    int t = t0 + t4;
    if (t + 3 < NT) {
      y2[base + t] = a0; y2[base + t + 1] = a1; y2[base + t + 2] = a2; y2[base + t + 3] = a3;
    } else {
      if (t < NT) y2[base + t] = a0;
      if (t + 1 < NT) y2[base + t + 1] = a1;
      if (t + 2 < NT) y2[base + t + 2] = a2;
      if (t + 3 < NT) y2[base + t + 3] = a3;
    }
  }
}

// ---------------- K3: fused groupnorm stats + apply + gelu -> cat ----------------
__global__ __launch_bounds__(256) void k_gn(const float* __restrict__ y2base,
    const float* __restrict__ gA, const float* __restrict__ gB, const float* __restrict__ gC,
    const float* __restrict__ bA, const float* __restrict__ bB, const float* __restrict__ bC,
    float* __restrict__ cat) {
  int b = blockIdx.x, tile = blockIdx.y, z = blockIdx.z, tid = threadIdx.x;
  const float* gng = (z == 0) ? gA : ((z == 1) ? gB : gC);
  const float* gnb = (z == 0) ? bA : ((z == 1) ? bB : bC);
  const float* y2 = y2base + (size_t)z * SZF + (size_t)b * 96 * NT;
  __shared__ float redS[256], redQ[256];
  __shared__ float muL[8], rsL[8];
  __shared__ float yL[96 * 65];
  // Phase A: per-group stats over the full (b,z) slab (single pass sum/sumsq)
  for (int g = 0; g < 8; ++g) {
    const float* gb = y2 + g * 12 * NT;
    float s = 0, q = 0;
    for (int i = tid; i < 12 * NT; i += 256) { float v = gb[i]; s += v; q = fmaf(v, v, q); }
    redS[tid] = s; redQ[tid] = q;
    __syncthreads();
    for (int st = 128; st > 0; st >>= 1) {
      if (tid < st) { redS[tid] += redS[tid + st]; redQ[tid] += redQ[tid + st]; }
      __syncthreads();
    }
    if (tid == 0) {
      float mu = redS[0] / 4356.0f;
      float var = redQ[0] / 4356.0f - mu * mu;
      muL[g] = mu;
      rsL[g] = rsqrtf(fmaxf(var, 0.0f) + 1e-5f);
    }
    __syncthreads();
  }
  // Phase B: apply + gelu for this tile (transpose via LDS)
  int t0 = tile * 64;
  for (int i = tid; i < 96 * 64; i += 256) {
    int cc = i >> 6, t = i & 63;
    int tt = t0 + t;
    yL[cc * 65 + t] = (tt < NT) ? y2[cc * NT + tt] : 0.0f;
  }
  __syncthreads();
  for (int i = tid; i < 64 * 96; i += 256) {
    int tt = i / 96, cc = i % 96;
    int t = t0 + tt;
    if (t < NT) {
      int g = cc / 12;
      float v = (yL[cc * 65 + tt] - muL[g]) * rsL[g] * gng[cc] + gnb[cc];
      cat[((size_t)b * NT + t) * 288 + z * 96 + cc] = gelu_f(v);
    }
  }
}

// ---------------- K4: merge GEMM + LN + GELU + qproj + sigmoid -> angles;
//                  blocks 726..741 run the correlation path -> fusedG ----------------
struct CorrSM { float mu[180]; float inv[180]; float S[NT * 12]; float fcv[78]; };
struct MergeSM {
  float catL[8][288];
  float vL[8][132];
  float hL[8][132];
  float muS[8], rsS[8];
};
union MCSM { MergeSM m; CorrSM c; };

__global__ __launch_bounds__(256) void k_merge(const float* __restrict__ cat,
    const float* __restrict__ mw, const float* __restrict__ mb,
    const float* __restrict__ lng, const float* __restrict__ lnb,
    const float* __restrict__ qw, const float* __restrict__ qb,
    float2* __restrict__ angG,
    const float* __restrict__ x,
    const float* __restrict__ fcw, const float* __restrict__ fcb,
    float* __restrict__ fusedG) {
  __shared__ MCSM sm;
  int tid = threadIdx.x;
  if (blockIdx.x < 726) {
    int blk = blockIdx.x;
    for (int i = tid; i < 8 * 288; i += 256) {
      int r = i / 288, k = i % 288;
      sm.m.catL[r][k] = cat[((size_t)blk * 8 + r) * 288 + k];
    }
    __syncthreads();
    int jj = tid & 127, rg = tid >> 7;
    float bias = mb[jj];
    float acc[4] = {bias, bias, bias, bias};
    {
      const float4* c0 = reinterpret_cast<const float4*>(&sm.m.catL[rg * 4 + 0][0]);
      const float4* c1 = reinterpret_cast<const float4*>(&sm.m.catL[rg * 4 + 1][0]);
      const float4* c2 = reinterpret_cast<const float4*>(&sm.m.catL[rg * 4 + 2][0]);
      const float4* c3 = reinterpret_cast<const float4*>(&sm.m.catL[rg * 4 + 3][0]);
      for (int k4 = 0; k4 < 72; ++k4) {
        float w0 = mw[(k4 * 4 + 0) * 128 + jj];
        float w1 = mw[(k4 * 4 + 1) * 128 + jj];
        float w2 = mw[(k4 * 4 + 2) * 128 + jj];
        float w3 = mw[(k4 * 4 + 3) * 128 + jj];
        float4 v0 = c0[k4], v1 = c1[k4], v2 = c2[k4], v3 = c3[k4];
        acc[0] = fmaf(v0.x, w0, fmaf(v0.y, w1, fmaf(v0.z, w2, fmaf(v0.w, w3, acc[0]))));
        acc[1] = fmaf(v1.x, w0, fmaf(v1.y, w1, fmaf(v1.z, w2, fmaf(v1.w, w3, acc[1]))));
        acc[2] = fmaf(v2.x, w0, fmaf(v2.y, w1, fmaf(v2.z, w2, fmaf(v2.w, w3, acc[2]))));
        acc[3] = fmaf(v3.x, w0, fmaf(v3.y, w1, fmaf(v3.z, w2, fmaf(v3.w, w3, acc[3]))));
      }
    }
#pragma unroll
    for (int r = 0; r < 4; ++r) sm.m.vL[rg * 4 + r][jj] = acc[r];
    __syncthreads();
    if (tid < 8) {
      float s = 0;
      for (int k = 0; k < 128; ++k) s += sm.m.vL[tid][k];
      float mu = s / 128.0f;
      float q = 0;
      for (int k = 0; k < 128; ++k) { float d = sm.m.vL[tid][k] - mu; q = fmaf(d, d, q); }
      sm.m.muS[tid] = mu;
      sm.m.rsS[tid] = rsqrtf(q / 128.0f + 1e-5f);
    }
    __syncthreads();
    float g = lng[jj], bb2 = lnb[jj];
#pragma unroll
    for (int r = 0; r < 4; ++r) {
      int row = rg * 4 + r;
      float h = (acc[r] - sm.m.muS[row]) * sm.m.rsS[row] * g + bb2;
      sm.m.hL[row][jj] = gelu_f(h);
    }
    __syncthreads();
    int o = tid & 63;
    int r0 = (tid >> 6) * 2;
    for (int rr = 0; rr < 2; ++rr) {
      int row = r0 + rr;
      float u = qb[o];
      const float4* h4 = reinterpret_cast<const float4*>(&sm.m.hL[row][0]);
      for (int k4 = 0; k4 < 32; ++k4) {
        float4 hv = h4[k4];
        u = fmaf(hv.x, qw[(k4 * 4 + 0) * 64 + o],
            fmaf(hv.y, qw[(k4 * 4 + 1) * 64 + o],
            fmaf(hv.z, qw[(k4 * 4 + 2) * 64 + o],
            fmaf(hv.w, qw[(k4 * 4 + 3) * 64 + o], u))));
      }
      float tp = 6.2831853071795864769f / (1.0f + expf(-u));
      float hf = tp * 0.5f;
      int grow = blk * 8 + row;
      angG[(size_t)grow * 64 + o] = make_float2(cosf(hf), sinf(hf));
    }
  } else {
    int b = blockIdx.x - 726;
    if (tid < 180) {
      float s = 0;
      const float* px = x + (size_t)b * NT * NC + tid;
      for (int t = 0; t < NT; ++t) s += px[t * NC];
      float mu = s / 363.0f;
      float q = 0;
      for (int t = 0; t < NT; ++t) { float d = px[t * NC] - mu; q = fmaf(d, d, q); }
      float sd = sqrtf(q / 362.0f);
      sd = fmaxf(sd, 1e-8f);
      sm.c.mu[tid] = mu; sm.c.inv[tid] = 1.0f / sd;
    }
    __syncthreads();
    for (int t = tid; t < NT; t += 256) {
      const float* px = x + (size_t)(b * NT + t) * NC;
#pragma unroll
      for (int i = 0; i < 12; ++i) {
        float s = 0;
#pragma unroll
        for (int u = 0; u < 15; ++u) {
          int cidx = i * 15 + u;
          s += (px[cidx] - sm.c.mu[cidx]) * sm.c.inv[cidx];
        }
        sm.c.S[t * 12 + i] = s;
      }
    }
    __syncthreads();
    if (tid < 78) {
      int i = 0, rem = tid;
      while (rem >= 12 - i) { rem -= 12 - i; ++i; }
      int j = i + rem;
      float acc = 0;
      for (int t = 0; t < NT; ++t) acc = fmaf(sm.c.S[t * 12 + i], sm.c.S[t * 12 + j], acc);
      sm.c.fcv[tid] = acc * (1.0f / (225.0f * 362.0f));
    }
    __syncthreads();
    if (tid < 64) {
      float v = fcb[tid];
#pragma unroll
      for (int k = 0; k < 78; ++k) v = fmaf(sm.c.fcv[k], fcw[k * 64 + tid], v);
      fusedG[b * 192 + 128 + tid] = gelu_f(v);
    }
  }
}

// ---------------- K5: quantum ansatz (v2: 16 amps/lane, 4 rows/wave, Horner) ----------------
__global__ __launch_bounds__(64) void k_quantum(const float2* __restrict__ angG,
                                                const float* __restrict__ pc4,
                                                float* __restrict__ accG) {
  const int lane = threadIdx.x;
  const int g = lane >> 4;
  const int ll = lane & 15;
  const int row0 = blockIdx.x * 4;
  __shared__ float2 angL[4][66];  // pad 66 so the 4 subgroup bases hit distinct banks
#pragma unroll
  for (int q = 0; q < 4; ++q)
    angL[q][lane] = angG[(size_t)(row0 + q) * 64 + lane];
  __syncthreads();
  float p0 = pc4[0], p1 = pc4[1], p2 = pc4[2], p3 = pc4[3];
  float re[16], im[16];
#pragma unroll
  for (int j = 0; j < 16; ++j) { re[j] = 0.0f; im[j] = 0.0f; }
  // Horner: acc = p0 + U(p1 + U(p2 + U*p3)) |0>
  if (ll == 0) re[0] = p3;
  const float2* ang = &angL[g][0];
  for (int rep = 0; rep < 3; ++rep) {
    qlayer(re, im, ang, lane);
    qlayer(re, im, ang + 32, lane);
    float pc = (rep == 0) ? p2 : (rep == 1) ? p1 : p0;
    if (ll == 0) re[0] += pc;
  }
  int row = row0 + g;
  float4* dst = reinterpret_cast<float4*>(accG + ((size_t)row * 256 + ll * 16) * 2);
#pragma unroll
  for (int h = 0; h < 8; ++h)
    dst[h] = make_float4(re[2 * h], im[2 * h], re[2 * h + 1], im[2 * h + 1]);
}

// ---------------- K6: tail — mix + qff + pauli + qout + final MLP -> out ----------------
__global__ __launch_bounds__(256) void k_tail(const float* __restrict__ accG,
    const float* __restrict__ mr, const float* __restrict__ mi,
    const float* __restrict__ qff,
    const float* __restrict__ qout_w, const float* __restrict__ qout_b,
    const float* __restrict__ fusedG,
    const float* __restrict__ w1, const float* __restrict__ b1,
    const float* __restrict__ lng, const float* __restrict__ lnb,
    const float* __restrict__ w2, const float* __restrict__ b2,
    float* __restrict__ out) {
  int b = blockIdx.x, tid = threadIdx.x;
  __shared__ float psiL[256][2];
  __shared__ float red[256];
  __shared__ float qcL[32], qsL[32], exps[24];
  __shared__ float tL[128], cL[64], hL[128];
  {
    const float2* av = reinterpret_cast<const float2*>(accG) + (size_t)b * NT * 256 + tid;
    float sr = 0, si = 0;
#pragma unroll 3
    for (int t = 0; t < NT; ++t) {
      float2 a = av[(size_t)t * 256];
      float m_r = mr[t], m_i = mi[t];
      sr = fmaf(m_r, a.x, fmaf(-m_i, a.y, sr));
      si = fmaf(m_r, a.y, fmaf(m_i, a.x, si));
    }
    psiL[tid][0] = sr; psiL[tid][1] = si;
    red[tid] = sr * sr + si * si;
  }
  if (tid < 32) { float h = qff[tid] * 0.5f; qcL[tid] = cosf(h); qsL[tid] = sinf(h); }
  __syncthreads();
  for (int s2 = 128; s2 > 0; s2 >>= 1) { if (tid < s2) red[tid] += red[tid + s2]; __syncthreads(); }
  float inv = 1.0f / (sqrtf(red[0]) + 1e-9f);
  __syncthreads();
  if (tid < 64) {
    int lane = tid;
    float re[4], im[4];
#pragma unroll
    for (int j = 0; j < 4; ++j) {
      re[j] = psiL[lane * 4 + j][0] * inv;
      im[j] = psiL[lane * 4 + j][1] * inv;
    }
    sim14_layer(re, im, qcL, qsL, lane);
#pragma unroll
    for (int j = 0; j < 4; ++j) { psiL[lane * 4 + j][0] = re[j]; psiL[lane * 4 + j][1] = im[j]; }
  }
  __syncthreads();
  if (tid < 64) {
    int lane = tid;
    for (int w = 0; w < 8; ++w) {
      int p = 7 - w;
      float cr = 0, ci = 0, z = 0;
#pragma unroll
      for (int k = 0; k < 2; ++k) {
        int pr = lane + k * 64;
        int lowmask = (1 << p) - 1;
        int i0 = ((pr >> p) << (p + 1)) | (pr & lowmask);
        int i1 = i0 | (1 << p);
        float r0 = psiL[i0][0], I0 = psiL[i0][1], r1 = psiL[i1][0], I1 = psiL[i1][1];
        cr += r0 * r1 + I0 * I1;
        ci += r0 * I1 - I0 * r1;
        z += r0 * r0 + I0 * I0 - r1 * r1 - I1 * I1;
      }
      for (int off = 32; off > 0; off >>= 1) {
        cr += __shfl_down(cr, off);
        ci += __shfl_down(ci, off);
        z  += __shfl_down(z, off);
      }
      if (lane == 0) { exps[w] = 2.0f * cr; exps[8 + w] = 2.0f * ci; exps[16 + w] = z; }
    }
  }
  __syncthreads();
  if (tid < 128) {
    float v = qout_b[tid];
#pragma unroll
    for (int k = 0; k < 24; ++k) v = fmaf(exps[k], qout_w[k * 128 + tid], v);
    tL[tid] = v;
  } else if (tid < 192) {
    cL[tid - 128] = fusedG[b * 192 + 128 + (tid - 128)];
  }
  __syncthreads();
  float v = 0.0f;
  if (tid < 128) {
    v = b1[tid];
    for (int k = 0; k < 128; ++k) v = fmaf(tL[k], w1[k * 128 + tid], v);
    for (int k = 0; k < 64; ++k)  v = fmaf(cL[k], w1[(128 + k) * 128 + tid], v);
    red[tid] = v;
  }
  __syncthreads();
  for (int s = 64; s > 0; s >>= 1) { if (tid < s) red[tid] += red[tid + s]; __syncthreads(); }
  float mu = red[0] / 128.0f;
  __syncthreads();
  float dv = v - mu;
  if (tid < 128) red[tid] = dv * dv;
  __syncthreads();
  for (int s = 64; s > 0; s >>= 1) { if (tid < s) red[tid] += red[tid + s]; __syncthreads(); }
  float var = red[0] / 128.0f;
  if (tid < 128) hL[tid] = gelu_f(dv * rsqrtf(var + 1e-5f) * lng[tid] + lnb[tid]);
  __syncthreads();
  if (tid < 64) {
    float o = b2[tid];
    for (int k = 0; k < 128; ++k) o = fmaf(hL[k], w2[k * 64 + tid], o);
    out[b * 64 + tid] = o;
  }
}

extern "C" void kernel_launch(void* const* d_in, const int* in_sizes, int n_in,
                              void* d_out, int out_size, void* d_ws, size_t ws_size,
                              hipStream_t stream) {
  const float* x       = (const float*)d_in[0];
  const float* net_w   = (const float*)d_in[1];
  const float* net_b   = (const float*)d_in[2];
  const float* dwa_w   = (const float*)d_in[3];
  const float* dwa_b   = (const float*)d_in[4];
  const float* pwa_w   = (const float*)d_in[5];
  const float* pwa_b   = (const float*)d_in[6];
  const float* gna_g   = (const float*)d_in[7];
  const float* gna_b   = (const float*)d_in[8];
  const float* dwb_w   = (const float*)d_in[9];
  const float* dwb_b   = (const float*)d_in[10];
  const float* pwb_w   = (const float*)d_in[11];
  const float* pwb_b   = (const float*)d_in[12];
  const float* gnb_g   = (const float*)d_in[13];
  const float* gnb_b   = (const float*)d_in[14];
  const float* dwc_w   = (const float*)d_in[15];
  const float* dwc_b   = (const float*)d_in[16];
  const float* pwc_w   = (const float*)d_in[17];
  const float* pwc_b   = (const float*)d_in[18];
  const float* gnc_g   = (const float*)d_in[19];
  const float* gnc_b   = (const float*)d_in[20];
  const float* merge_w = (const float*)d_in[21];
  const float* merge_b = (const float*)d_in[22];
  const float* mlng    = (const float*)d_in[23];
  const float* mlnb    = (const float*)d_in[24];
  const float* qproj_w = (const float*)d_in[25];
  const float* qproj_b = (const float*)d_in[26];
  const float* poly    = (const float*)d_in[27];
  const float* qff     = (const float*)d_in[28];
  const float* mix_re  = (const float*)d_in[29];
  const float* mix_im  = (const float*)d_in[30];
  const float* qout_w  = (const float*)d_in[31];
  const float* qout_b  = (const float*)d_in[32];
  const float* fc_w    = (const float*)d_in[33];
  const float* fc_b    = (const float*)d_in[34];
  const float* fus1_w  = (const float*)d_in[35];
  const float* fus1_b  = (const float*)d_in[36];
  const float* flng    = (const float*)d_in[37];
  const float* flnb    = (const float*)d_in[38];
  const float* fus2_w  = (const float*)d_in[39];
  const float* fus2_b  = (const float*)d_in[40];
  float* out = (float*)d_out;

  // workspace layout (floats):
  //  [0, 3*SZF)        y1a/y1b/y1c   (dead after k_pw); cat aliases exactly
  //  [3*SZF, 6*SZF)    y2a/y2b/y2c   (dead after k_gn)
  //  acc aliases [0, 2,973,696) — written by k_quantum after k_merge read cat
  //  [6*SZF ...)       angG, fused
  float* W = (float*)d_ws;
  float* y1b_  = W;                                // 3*SZF
  float* cat   = W;                                // alias
  float* y2b_  = W + 3 * (size_t)SZF;
  float* acc   = W;                                // alias, len 2,973,696 (< 6*SZF)
  float2* angG = (float2*)(W + 6 * (size_t)SZF);   // 371,712 float2
  float* fused = W + 6 * (size_t)SZF + 743424;     // 3,072

  k_emdw<<<dim3(NB, 12), 256, 0, stream>>>(x, net_w, net_b,
      dwa_w, dwa_b, dwb_w, dwb_b, dwc_w, dwc_b, y1b_);
  k_pw<<<dim3(NB, 6, 3), 256, 0, stream>>>(y1b_, pwa_w, pwb_w, pwc_w, pwa_b, pwb_b, pwc_b, y2b_);
  k_gn<<<dim3(NB, 6, 3), 256, 0, stream>>>(y2b_,
      gna_g, gnb_g, gnc_g, gna_b, gnb_b, gnc_b, cat);
  k_merge<<<726 + NB, 256, 0, stream>>>(cat, merge_w, merge_b, mlng, mlnb,
      qproj_w, qproj_b, angG, x, fc_w, fc_b, fused);
  k_quantum<<<NROW / 4, 64, 0, stream>>>(angG, poly, acc);
  k_tail<<<NB, 256, 0, stream>>>(acc, mix_re, mix_im, qff, qout_w, qout_b, fused,
                                 fus1_w, fus1_b, flng, flnb, fus2_w, fus2_b, out);
}

// Round 9
// 365.399 us; speedup vs baseline: 1.4747x; 1.0907x over previous
//
#include <hip/hip_runtime.h>
#include <math.h>

#define NB 16
#define NT 363
#define NC 180
#define SZF 557568   // NB*96*NT
#define NROW 5808    // NB*NT

__device__ __forceinline__ float gelu_f(float x) {
  return 0.5f * x * (1.0f + erff(x * 0.7071067811865475244f));
}

// ================= quantum gate primitives (v2 layout — measured best) =================
// k_quantum: 16 amps/lane. local j = state bits [3:0];
// lane bits [3:0] = state bits [7:4]; lane bits [5:4] = row-in-wave g.
// wire w acts on state bit p = 7-w.
// p<=3 local; p=4 lane^1 (DPP); p=5 lane^2 (DPP); p=6 lane^4 (DS); p=7 lane^8 (DS).

template<int CTRL>
__device__ __forceinline__ float dppf(float x) {
  return __int_as_float(__builtin_amdgcn_update_dpp(
      0, __float_as_int(x), CTRL, 0xF, 0xF, true));
}

template<int LB>
__device__ __forceinline__ float lx(float x) {
  if constexpr (LB == 0) return dppf<0xB1>(x);        // quad_perm xor 1
  else if constexpr (LB == 1) return dppf<0x4E>(x);   // quad_perm xor 2
  else if constexpr (LB == 2) return __shfl_xor(x, 4);
  else return __shfl_xor(x, 8);
}

template<int P>
__device__ __forceinline__ void ry_local(float* re, float* im, float c, float s) {
#pragma unroll
  for (int j = 0; j < 16; ++j) {
    if ((j & (1 << P)) == 0) {
      int k = j | (1 << P);
      float r0 = re[j], i0 = im[j], r1 = re[k], i1 = im[k];
      re[j] = fmaf(c, r0, -s * r1); im[j] = fmaf(c, i0, -s * i1);
      re[k] = fmaf(s, r0,  c * r1); im[k] = fmaf(s, i0,  c * i1);
    }
  }
}

template<int LB>
__device__ __forceinline__ void ry_lane(float* re, float* im, float c, float s, int lane) {
  float sg = (lane & (1 << LB)) ? s : -s;
#pragma unroll
  for (int j = 0; j < 16; ++j) {
    float br = lx<LB>(re[j]);
    float bi = lx<LB>(im[j]);
    re[j] = fmaf(c, re[j], sg * br);
    im[j] = fmaf(c, im[j], sg * bi);
  }
}

template<int Q, int P>  // control local bit Q, target local bit P
__device__ __forceinline__ void crx_ll(float* re, float* im, float cs, float sn) {
#pragma unroll
  for (int j = 0; j < 16; ++j) {
    if ((j & (1 << Q)) && !(j & (1 << P))) {
      int k = j | (1 << P);
      float r0 = re[j], i0 = im[j], r1 = re[k], i1 = im[k];
      re[j] = fmaf(cs, r0,  sn * i1); im[j] = fmaf(cs, i0, -sn * r1);
      re[k] = fmaf(cs, r1,  sn * i0); im[k] = fmaf(cs, i1, -sn * r0);
    }
  }
}

template<int LBQ, int P>  // control lane bit LBQ, target local bit P
__device__ __forceinline__ void crx_nl(float* re, float* im, float cs, float sn, int lane) {
  if (lane & (1 << LBQ)) {
#pragma unroll
    for (int j = 0; j < 16; ++j) {
      if ((j & (1 << P)) == 0) {
        int k = j | (1 << P);
        float r0 = re[j], i0 = im[j], r1 = re[k], i1 = im[k];
        re[j] = fmaf(cs, r0,  sn * i1); im[j] = fmaf(cs, i0, -sn * r1);
        re[k] = fmaf(cs, r1,  sn * i0); im[k] = fmaf(cs, i1, -sn * r0);
      }
    }
  }
}

template<int Q, int LBP>  // control local bit Q, target lane bit LBP
__device__ __forceinline__ void crx_ln(float* re, float* im, float cs, float sn) {
#pragma unroll
  for (int j = 0; j < 16; ++j) {
    if (j & (1 << Q)) {
      float br = lx<LBP>(re[j]);
      float bi = lx<LBP>(im[j]);
      re[j] = fmaf(cs, re[j],  sn * bi);
      im[j] = fmaf(cs, im[j], -sn * br);
    }
  }
}

template<int LBQ, int LBP>  // control lane bit LBQ, target lane bit LBP
__device__ __forceinline__ void crx_nn(float* re, float* im, float cs, float sn, int lane) {
  bool ctl = (lane & (1 << LBQ)) != 0;
#pragma unroll
  for (int j = 0; j < 16; ++j) {
    float br = lx<LBP>(re[j]);
    float bi = lx<LBP>(im[j]);
    if (ctl) {
      re[j] = fmaf(cs, re[j],  sn * bi);
      im[j] = fmaf(cs, im[j], -sn * br);
    }
  }
}

// one reference "layer" = RY ring, CRX(q,q+1) ring, RY ring, CRX(q,q-1) ring
__device__ __forceinline__ void qlayer(float* re, float* im,
                                       const float2* ang, int lane) {
  float2 a;
  a = ang[0];  ry_lane<3>(re, im, a.x, a.y, lane);
  a = ang[1];  ry_lane<2>(re, im, a.x, a.y, lane);
  a = ang[2];  ry_lane<1>(re, im, a.x, a.y, lane);
  a = ang[3];  ry_lane<0>(re, im, a.x, a.y, lane);
  a = ang[4];  ry_local<3>(re, im, a.x, a.y);
  a = ang[5];  ry_local<2>(re, im, a.x, a.y);
  a = ang[6];  ry_local<1>(re, im, a.x, a.y);
  a = ang[7];  ry_local<0>(re, im, a.x, a.y);
  a = ang[8];  crx_nn<3, 2>(re, im, a.x, a.y, lane);
  a = ang[9];  crx_nn<2, 1>(re, im, a.x, a.y, lane);
  a = ang[10]; crx_nn<1, 0>(re, im, a.x, a.y, lane);
  a = ang[11]; crx_nl<0, 3>(re, im, a.x, a.y, lane);
  a = ang[12]; crx_ll<3, 2>(re, im, a.x, a.y);
  a = ang[13]; crx_ll<2, 1>(re, im, a.x, a.y);
  a = ang[14]; crx_ll<1, 0>(re, im, a.x, a.y);
  a = ang[15]; crx_ln<0, 3>(re, im, a.x, a.y);
  a = ang[16]; ry_lane<3>(re, im, a.x, a.y, lane);
  a = ang[17]; ry_lane<2>(re, im, a.x, a.y, lane);
  a = ang[18]; ry_lane<1>(re, im, a.x, a.y, lane);
  a = ang[19]; ry_lane<0>(re, im, a.x, a.y, lane);
  a = ang[20]; ry_local<3>(re, im, a.x, a.y);
  a = ang[21]; ry_local<2>(re, im, a.x, a.y);
  a = ang[22]; ry_local<1>(re, im, a.x, a.y);
  a = ang[23]; ry_local<0>(re, im, a.x, a.y);
  a = ang[24]; crx_nl<3, 0>(re, im, a.x, a.y, lane);
  a = ang[25]; crx_nn<2, 3>(re, im, a.x, a.y, lane);
  a = ang[26]; crx_nn<1, 2>(re, im, a.x, a.y, lane);
  a = ang[27]; crx_nn<0, 1>(re, im, a.x, a.y, lane);
  a = ang[28]; crx_ln<3, 0>(re, im, a.x, a.y);
  a = ang[29]; crx_ll<2, 3>(re, im, a.x, a.y);
  a = ang[30]; crx_ll<1, 2>(re, im, a.x, a.y);
  a = ang[31]; crx_ll<0, 1>(re, im, a.x, a.y);
}

// --- v1 layout helpers (4 amps/lane) for the tail qff step ---
template<int P>
__device__ __forceinline__ void ryg(float* re, float* im, float c, float s, int lane) {
  if constexpr (P >= 2) {
    constexpr int mask = 1 << (P - 2);
    float sg = ((lane >> (P - 2)) & 1) ? s : -s;
#pragma unroll
    for (int j = 0; j < 4; ++j) {
      float br = __shfl_xor(re[j], mask);
      float bi = __shfl_xor(im[j], mask);
      re[j] = fmaf(c, re[j], sg * br);
      im[j] = fmaf(c, im[j], sg * bi);
    }
  } else {
#pragma unroll
    for (int k = 0; k < 2; ++k) {
      const int a = (P == 0) ? 2 * k : k;
      const int b = (P == 0) ? a + 1 : a + 2;
      float r0 = re[a], i0 = im[a], r1 = re[b], i1 = im[b];
      re[a] = fmaf(c, r0, -s * r1); im[a] = fmaf(c, i0, -s * i1);
      re[b] = fmaf(s, r0,  c * r1); im[b] = fmaf(s, i0,  c * i1);
    }
  }
}

template<int PC, int PT>
__device__ __forceinline__ void crxg(float* re, float* im, float cs, float sn, int lane) {
  if constexpr (PT >= 2) {
    constexpr int mask = 1 << (PT - 2);
#pragma unroll
    for (int j = 0; j < 4; ++j) {
      float br = __shfl_xor(re[j], mask);
      float bi = __shfl_xor(im[j], mask);
      bool ctrl;
      if constexpr (PC >= 2) ctrl = ((lane >> (PC - 2)) & 1) != 0;
      else                   ctrl = ((j >> PC) & 1) != 0;
      if (ctrl) {
        float nr = fmaf(cs, re[j],  sn * bi);
        float ni = fmaf(cs, im[j], -sn * br);
        re[j] = nr; im[j] = ni;
      }
    }
  } else {
#pragma unroll
    for (int k = 0; k < 2; ++k) {
      const int a = (PT == 0) ? 2 * k : k;
      const int b = (PT == 0) ? a + 1 : a + 2;
      bool ctrl;
      if constexpr (PC >= 2) ctrl = ((lane >> (PC - 2)) & 1) != 0;
      else                   ctrl = ((a >> PC) & 1) != 0;
      if (ctrl) {
        float r0 = re[a], i0 = im[a], r1 = re[b], i1 = im[b];
        re[a] = fmaf(cs, r0,  sn * i1); im[a] = fmaf(cs, i0, -sn * r1);
        re[b] = fmaf(cs, r1,  sn * i0); im[b] = fmaf(cs, i1, -sn * r0);
      }
    }
  }
}

__device__ __forceinline__ void sim14_layer(float* re, float* im,
                                            const float* Cr, const float* Sr, int lane) {
#define ARY1(q, pi) ryg<7-(q)>(re, im, Cr[pi], Sr[pi], lane)
#define ACX1(cq, tq, pi) crxg<7-(cq), 7-(tq)>(re, im, Cr[pi], Sr[pi], lane)
  ARY1(0,0); ARY1(1,1); ARY1(2,2); ARY1(3,3); ARY1(4,4); ARY1(5,5); ARY1(6,6); ARY1(7,7);
  ACX1(0,1,8); ACX1(1,2,9); ACX1(2,3,10); ACX1(3,4,11); ACX1(4,5,12); ACX1(5,6,13); ACX1(6,7,14); ACX1(7,0,15);
  ARY1(0,16); ARY1(1,17); ARY1(2,18); ARY1(3,19); ARY1(4,20); ARY1(5,21); ARY1(6,22); ARY1(7,23);
  ACX1(0,7,24); ACX1(1,0,25); ACX1(2,1,26); ACX1(3,2,27); ACX1(4,3,28); ACX1(5,4,29); ACX1(6,5,30); ACX1(7,6,31);
#undef ARY1
#undef ACX1
}

// ---------------- K1: fused embed + depthwise conv (blocks y<12) + corr (y==12) ----------------
struct CorrSM { float mu[180]; float inv[180]; float S[NT * 12]; float fcv[78]; };
struct EmdwSM {
  float xs[NT * 15];
  float nwL[120], nbL[8];
  float hrow[8][368];
  float wL[3][8][8];
  float bL[3][8];
};
union EDSM { EmdwSM e; CorrSM c; };

__global__ __launch_bounds__(256) void k_emdw(const float* __restrict__ x,
    const float* __restrict__ nw, const float* __restrict__ nb,
    const float* __restrict__ wa, const float* __restrict__ ba,
    const float* __restrict__ wb, const float* __restrict__ bb,
    const float* __restrict__ wc, const float* __restrict__ bc,
    float* __restrict__ y1base,
    const float* __restrict__ fcw, const float* __restrict__ fcb,
    float* __restrict__ fusedG) {
  __shared__ EDSM sm;
  int b = blockIdx.x, kg = blockIdx.y, tid = threadIdx.x;
  if (kg < 12) {
    for (int i = tid; i < 120; i += 256) sm.e.nwL[i] = nw[kg * 120 + i];
    for (int i = tid; i < 8; i += 256) sm.e.nbL[i] = nb[kg * 8 + i];
    for (int i = tid; i < 168; i += 256) {
      int z = i / 56, r = i % 56, d = r / 7, k = r % 7;
      const float* w = (z == 0) ? wa : ((z == 1) ? wb : wc);
      sm.e.wL[z][d][k] = w[(kg * 8 + d) * 7 + k];
    }
    for (int i = tid; i < 24; i += 256) {
      int z = i / 8, d = i % 8;
      const float* bias = (z == 0) ? ba : ((z == 1) ? bb : bc);
      sm.e.bL[z][d] = bias[kg * 8 + d];
    }
    for (int i = tid; i < NT * 15; i += 256) {
      int t = i / 15, u = i % 15;
      sm.e.xs[i] = x[((size_t)b * NT + t) * NC + kg * 15 + u];
    }
    __syncthreads();
    for (int i = tid; i < 8 * NT; i += 256) {
      int t = i % NT, d = i / NT;
      float acc2 = sm.e.nbL[d];
#pragma unroll
      for (int u = 0; u < 15; ++u) acc2 = fmaf(sm.e.xs[t * 15 + u], sm.e.nwL[u * 8 + d], acc2);
      sm.e.hrow[d][t] = gelu_f(acc2);
    }
    __syncthreads();
    for (int i = tid; i < 8 * NT; i += 256) {
      int t = i % NT, d = i / NT;
      int c = kg * 8 + d;
      float a0 = sm.e.bL[0][d], a1 = sm.e.bL[1][d], a2 = sm.e.bL[2][d];
#pragma unroll
      for (int k = 0; k < 7; ++k) {
        int i1 = t + (k - 3);
        int i4 = t + (k - 3) * 4;
        int i16 = t + (k - 3) * 16;
        if (i1 >= 0 && i1 < NT)  a0 = fmaf(sm.e.hrow[d][i1],  sm.e.wL[0][d][k], a0);
        if (i4 >= 0 && i4 < NT)  a1 = fmaf(sm.e.hrow[d][i4],  sm.e.wL[1][d][k], a1);
        if (i16 >= 0 && i16 < NT) a2 = fmaf(sm.e.hrow[d][i16], sm.e.wL[2][d][k], a2);
      }
      size_t base = ((size_t)b * 96 + c) * NT + t;
      y1base[base] = a0;
      y1base[SZF + base] = a1;
      y1base[2 * SZF + base] = a2;
    }
  } else {
    // correlation path for batch b -> fusedG[b*192+128 .. +192]
    if (tid < 180) {
      float s = 0;
      const float* px = x + (size_t)b * NT * NC + tid;
      for (int t = 0; t < NT; ++t) s += px[t * NC];
      float mu = s / 363.0f;
      float q = 0;
      for (int t = 0; t < NT; ++t) { float d = px[t * NC] - mu; q = fmaf(d, d, q); }
      float sd = sqrtf(q / 362.0f);
      sd = fmaxf(sd, 1e-8f);
      sm.c.mu[tid] = mu; sm.c.inv[tid] = 1.0f / sd;
    }
    __syncthreads();
    for (int t = tid; t < NT; t += 256) {
      const float* px = x + (size_t)(b * NT + t) * NC;
#pragma unroll
      for (int i = 0; i < 12; ++i) {
        float s = 0;
#pragma unroll
        for (int u = 0; u < 15; ++u) {
          int cidx = i * 15 + u;
          s += (px[cidx] - sm.c.mu[cidx]) * sm.c.inv[cidx];
        }
        sm.c.S[t * 12 + i] = s;
      }
    }
    __syncthreads();
    if (tid < 78) {
      int i = 0, rem = tid;
      while (rem >= 12 - i) { rem -= 12 - i; ++i; }
      int j = i + rem;
      float acc = 0;
      for (int t = 0; t < NT; ++t) acc = fmaf(sm.c.S[t * 12 + i], sm.c.S[t * 12 + j], acc);
      sm.c.fcv[tid] = acc * (1.0f / (225.0f * 362.0f));
    }
    __syncthreads();
    if (tid < 64) {
      float v = fcb[tid];
#pragma unroll
      for (int k = 0; k < 78; ++k) v = fmaf(sm.c.fcv[k], fcw[k * 64 + tid], v);
      fusedG[b * 192 + 128 + tid] = gelu_f(v);
    }
  }
}

// ---------------- K2: pointwise 96x96, branch-batched (R6 version — measured good) ----------------
__global__ __launch_bounds__(256) void k_pw(const float* __restrict__ y1base,
    const float* __restrict__ wA, const float* __restrict__ wB, const float* __restrict__ wC,
    const float* __restrict__ bA, const float* __restrict__ bB, const float* __restrict__ bC,
    float* __restrict__ y2base) {
  int b = blockIdx.x, tile = blockIdx.y, z = blockIdx.z, tid = threadIdx.x;
  const float* pw_w = (z == 0) ? wA : ((z == 1) ? wB : wC);
  const float* pw_b = (z == 0) ? bA : ((z == 1) ? bB : bC);
  const float* y1 = y1base + (size_t)z * SZF;
  float* y2 = y2base + (size_t)z * SZF;
  int t0 = tile * 64;
  __shared__ float y1t[96 * 64];
  __shared__ float pwL[96 * 97];  // pad 97 to break 96-stride bank aliasing
  for (int i = tid; i < 96 * 96; i += 256) {
    int o = i / 96, cc = i % 96;
    pwL[o * 97 + cc] = pw_w[i];
  }
  for (int i = tid; i < 96 * 64; i += 256) {
    int cc = i >> 6, t = i & 63;
    int tt = t0 + t;
    y1t[i] = (tt < NT) ? y1[(b * 96 + cc) * NT + tt] : 0.0f;
  }
  __syncthreads();
  int o16 = tid >> 4, t4 = (tid & 15) * 4;
  for (int pass = 0; pass < 6; ++pass) {
    int o = pass * 16 + o16;
    float bias = pw_b[o];
    float a0 = bias, a1 = bias, a2 = bias, a3 = bias;
    const float* wrow = &pwL[o * 97];
#pragma unroll 4
    for (int cc = 0; cc < 96; ++cc) {
      const float4 vy = *reinterpret_cast<const float4*>(&y1t[cc * 64 + t4]);
      float w = wrow[cc];
      a0 = fmaf(w, vy.x, a0); a1 = fmaf(w, vy.y, a1);
      a2 = fmaf(w, vy.z, a2); a3 = fmaf(w, vy.w, a3);
    }
    int base = (b * 96 + o) * NT;
    int t = t0 + t4;
    if (t + 3 < NT) {
      y2[base + t] = a0; y2[base + t + 1] = a1; y2[base + t + 2] = a2; y2[base + t + 3] = a3;
    } else {
      if (t < NT) y2[base + t] = a0;
      if (t + 1 < NT) y2[base + t + 1] = a1;
      if (t + 2 < NT) y2[base + t + 2] = a2;
      if (t + 3 < NT) y2[base + t + 3] = a3;
    }
  }
}

// ---------------- K3: fused groupnorm stats + apply + gelu -> cat ----------------
__global__ __launch_bounds__(256) void k_gn(const float* __restrict__ y2base,
    const float* __restrict__ gA, const float* __restrict__ gB, const float* __restrict__ gC,
    const float* __restrict__ bA, const float* __restrict__ bB, const float* __restrict__ bC,
    float* __restrict__ cat) {
  int b = blockIdx.x, tile = blockIdx.y, z = blockIdx.z, tid = threadIdx.x;
  const float* gng = (z == 0) ? gA : ((z == 1) ? gB : gC);
  const float* gnb = (z == 0) ? bA : ((z == 1) ? bB : bC);
  const float* y2 = y2base + (size_t)z * SZF + (size_t)b * 96 * NT;
  __shared__ float redS[256], redQ[256];
  __shared__ float muL[8], rsL[8];
  __shared__ float yL[96 * 65];
  for (int g = 0; g < 8; ++g) {
    const float* gb = y2 + g * 12 * NT;
    float s = 0, q = 0;
    for (int i = tid; i < 12 * NT; i += 256) { float v = gb[i]; s += v; q = fmaf(v, v, q); }
    redS[tid] = s; redQ[tid] = q;
    __syncthreads();
    for (int st = 128; st > 0; st >>= 1) {
      if (tid < st) { redS[tid] += redS[tid + st]; redQ[tid] += redQ[tid + st]; }
      __syncthreads();
    }
    if (tid == 0) {
      float mu = redS[0] / 4356.0f;
      float var = redQ[0] / 4356.0f - mu * mu;
      muL[g] = mu;
      rsL[g] = rsqrtf(fmaxf(var, 0.0f) + 1e-5f);
    }
    __syncthreads();
  }
  int t0 = tile * 64;
  for (int i = tid; i < 96 * 64; i += 256) {
    int cc = i >> 6, t = i & 63;
    int tt = t0 + t;
    yL[cc * 65 + t] = (tt < NT) ? y2[cc * NT + tt] : 0.0f;
  }
  __syncthreads();
  for (int i = tid; i < 64 * 96; i += 256) {
    int tt = i / 96, cc = i % 96;
    int t = t0 + tt;
    if (t < NT) {
      int g = cc / 12;
      float v = (yL[cc * 65 + tt] - muL[g]) * rsL[g] * gng[cc] + gnb[cc];
      cat[((size_t)b * NT + t) * 288 + z * 96 + cc] = gelu_f(v);
    }
  }
}

// ---------------- K4: merge GEMM + LN + GELU + qproj + sigmoid (scalar, R4-proven) ----------------
__global__ __launch_bounds__(256) void k_merge(const float* __restrict__ cat,
    const float* __restrict__ mw, const float* __restrict__ mb,
    const float* __restrict__ lng, const float* __restrict__ lnb,
    const float* __restrict__ qw, const float* __restrict__ qb,
    float2* __restrict__ angG) {
  int blk = blockIdx.x, tid = threadIdx.x;
  __shared__ float catL[8][288];
  __shared__ float vL[8][129];
  __shared__ float hL[8][129];
  __shared__ float muS[8], rsS[8];
  for (int i = tid; i < 8 * 288; i += 256) {
    int r = i / 288, k = i % 288;
    catL[r][k] = cat[((size_t)blk * 8 + r) * 288 + k];
  }
  __syncthreads();
  int jj = tid & 127, rg = tid >> 7;
  float bias = mb[jj];
  float acc[4] = {bias, bias, bias, bias};
  for (int k = 0; k < 288; ++k) {
    float w = mw[k * 128 + jj];
#pragma unroll
    for (int r = 0; r < 4; ++r) acc[r] = fmaf(catL[rg * 4 + r][k], w, acc[r]);
  }
#pragma unroll
  for (int r = 0; r < 4; ++r) vL[rg * 4 + r][jj] = acc[r];
  __syncthreads();
  if (tid < 8) {
    float s = 0;
    for (int k = 0; k < 128; ++k) s += vL[tid][k];
    float mu = s / 128.0f;
    float q = 0;
    for (int k = 0; k < 128; ++k) { float d = vL[tid][k] - mu; q = fmaf(d, d, q); }
    muS[tid] = mu;
    rsS[tid] = rsqrtf(q / 128.0f + 1e-5f);
  }
  __syncthreads();
  float g = lng[jj], bb2 = lnb[jj];
#pragma unroll
  for (int r = 0; r < 4; ++r) {
    int row = rg * 4 + r;
    float h = (acc[r] - muS[row]) * rsS[row] * g + bb2;
    hL[row][jj] = gelu_f(h);
  }
  __syncthreads();
  int o = tid & 63;
  int r0 = (tid >> 6) * 2;
  for (int rr = 0; rr < 2; ++rr) {
    int row = r0 + rr;
    float u = qb[o];
    for (int k = 0; k < 128; ++k) u = fmaf(hL[row][k], qw[k * 64 + o], u);
    float tp = 6.2831853071795864769f / (1.0f + expf(-u));
    float hf = tp * 0.5f;
    int grow = blk * 8 + row;
    angG[(size_t)grow * 64 + o] = make_float2(cosf(hf), sinf(hf));
  }
}

// ---------------- K5: quantum ansatz (v2: 16 amps/lane, 4 rows/wave, Horner) ----------------
__global__ __launch_bounds__(64) void k_quantum(const float2* __restrict__ angG,
                                                const float* __restrict__ pc4,
                                                float* __restrict__ accG) {
  const int lane = threadIdx.x;
  const int g = lane >> 4;
  const int ll = lane & 15;
  const int row0 = blockIdx.x * 4;
  __shared__ float2 angL[4][66];  // pad 66 so the 4 subgroup bases hit distinct banks
#pragma unroll
  for (int q = 0; q < 4; ++q)
    angL[q][lane] = angG[(size_t)(row0 + q) * 64 + lane];
  __syncthreads();
  float p0 = pc4[0], p1 = pc4[1], p2 = pc4[2], p3 = pc4[3];
  float re[16], im[16];
#pragma unroll
  for (int j = 0; j < 16; ++j) { re[j] = 0.0f; im[j] = 0.0f; }
  // Horner: acc = p0 + U(p1 + U(p2 + U*p3)) |0>
  if (ll == 0) re[0] = p3;
  const float2* ang = &angL[g][0];
  for (int rep = 0; rep < 3; ++rep) {
    qlayer(re, im, ang, lane);
    qlayer(re, im, ang + 32, lane);
    float pc = (rep == 0) ? p2 : (rep == 1) ? p1 : p0;
    if (ll == 0) re[0] += pc;
  }
  int row = row0 + g;
  float4* dst = reinterpret_cast<float4*>(accG + ((size_t)row * 256 + ll * 16) * 2);
#pragma unroll
  for (int h = 0; h < 8; ++h)
    dst[h] = make_float4(re[2 * h], im[2 * h], re[2 * h + 1], im[2 * h + 1]);
}

// ---------------- K6: tail — mix + qff + pauli + qout + final MLP -> out ----------------
__global__ __launch_bounds__(256) void k_tail(const float* __restrict__ accG,
    const float* __restrict__ mr, const float* __restrict__ mi,
    const float* __restrict__ qff,
    const float* __restrict__ qout_w, const float* __restrict__ qout_b,
    const float* __restrict__ fusedG,
    const float* __restrict__ w1, const float* __restrict__ b1,
    const float* __restrict__ lng, const float* __restrict__ lnb,
    const float* __restrict__ w2, const float* __restrict__ b2,
    float* __restrict__ out) {
  int b = blockIdx.x, tid = threadIdx.x;
  __shared__ float psiL[256][2];
  __shared__ float red[256];
  __shared__ float qcL[32], qsL[32], exps[24];
  __shared__ float tL[128], cL[64], hL[128];
  {
    const float2* av = reinterpret_cast<const float2*>(accG) + (size_t)b * NT * 256 + tid;
    // two independent accumulator pairs to break the fma dependency chain
    float sr0 = 0, si0 = 0, sr1 = 0, si1 = 0;
#pragma unroll 4
    for (int t = 0; t < NT - 1; t += 2) {
      float2 a0 = av[(size_t)t * 256];
      float2 a1 = av[(size_t)(t + 1) * 256];
      float m0r = mr[t], m0i = mi[t];
      float m1r = mr[t + 1], m1i = mi[t + 1];
      sr0 = fmaf(m0r, a0.x, fmaf(-m0i, a0.y, sr0));
      si0 = fmaf(m0r, a0.y, fmaf(m0i, a0.x, si0));
      sr1 = fmaf(m1r, a1.x, fmaf(-m1i, a1.y, sr1));
      si1 = fmaf(m1r, a1.y, fmaf(m1i, a1.x, si1));
    }
    {
      float2 a = av[(size_t)(NT - 1) * 256];
      float m_r = mr[NT - 1], m_i = mi[NT - 1];
      sr0 = fmaf(m_r, a.x, fmaf(-m_i, a.y, sr0));
      si0 = fmaf(m_r, a.y, fmaf(m_i, a.x, si0));
    }
    float sr = sr0 + sr1, si = si0 + si1;
    psiL[tid][0] = sr; psiL[tid][1] = si;
    red[tid] = sr * sr + si * si;
  }
  if (tid < 32) { float h = qff[tid] * 0.5f; qcL[tid] = cosf(h); qsL[tid] = sinf(h); }
  __syncthreads();
  for (int s2 = 128; s2 > 0; s2 >>= 1) { if (tid < s2) red[tid] += red[tid + s2]; __syncthreads(); }
  float inv = 1.0f / (sqrtf(red[0]) + 1e-9f);
  __syncthreads();
  if (tid < 64) {
    int lane = tid;
    float re[4], im[4];
#pragma unroll
    for (int j = 0; j < 4; ++j) {
      re[j] = psiL[lane * 4 + j][0] * inv;
      im[j] = psiL[lane * 4 + j][1] * inv;
    }
    sim14_layer(re, im, qcL, qsL, lane);
#pragma unroll
    for (int j = 0; j < 4; ++j) { psiL[lane * 4 + j][0] = re[j]; psiL[lane * 4 + j][1] = im[j]; }
  }
  __syncthreads();
  if (tid < 64) {
    int lane = tid;
    for (int w = 0; w < 8; ++w) {
      int p = 7 - w;
      float cr = 0, ci = 0, z = 0;
#pragma unroll
      for (int k = 0; k < 2; ++k) {
        int pr = lane + k * 64;
        int lowmask = (1 << p) - 1;
        int i0 = ((pr >> p) << (p + 1)) | (pr & lowmask);
        int i1 = i0 | (1 << p);
        float r0 = psiL[i0][0], I0 = psiL[i0][1], r1 = psiL[i1][0], I1 = psiL[i1][1];
        cr += r0 * r1 + I0 * I1;
        ci += r0 * I1 - I0 * r1;
        z += r0 * r0 + I0 * I0 - r1 * r1 - I1 * I1;
      }
      for (int off = 32; off > 0; off >>= 1) {
        cr += __shfl_down(cr, off);
        ci += __shfl_down(ci, off);
        z  += __shfl_down(z, off);
      }
      if (lane == 0) { exps[w] = 2.0f * cr; exps[8 + w] = 2.0f * ci; exps[16 + w] = z; }
    }
  }
  __syncthreads();
  if (tid < 128) {
    float v = qout_b[tid];
#pragma unroll
    for (int k = 0; k < 24; ++k) v = fmaf(exps[k], qout_w[k * 128 + tid], v);
    tL[tid] = v;
  } else if (tid < 192) {
    cL[tid - 128] = fusedG[b * 192 + 128 + (tid - 128)];
  }
  __syncthreads();
  float v = 0.0f;
  if (tid < 128) {
    v = b1[tid];
    for (int k = 0; k < 128; ++k) v = fmaf(tL[k], w1[k * 128 + tid], v);
    for (int k = 0; k < 64; ++k)  v = fmaf(cL[k], w1[(128 + k) * 128 + tid], v);
    red[tid] = v;
  }
  __syncthreads();
  for (int s = 64; s > 0; s >>= 1) { if (tid < s) red[tid] += red[tid + s]; __syncthreads(); }
  float mu = red[0] / 128.0f;
  __syncthreads();
  float dv = v - mu;
  if (tid < 128) red[tid] = dv * dv;
  __syncthreads();
  for (int s = 64; s > 0; s >>= 1) { if (tid < s) red[tid] += red[tid + s]; __syncthreads(); }
  float var = red[0] / 128.0f;
  if (tid < 128) hL[tid] = gelu_f(dv * rsqrtf(var + 1e-5f) * lng[tid] + lnb[tid]);
  __syncthreads();
  if (tid < 64) {
    float o = b2[tid];
    for (int k = 0; k < 128; ++k) o = fmaf(hL[k], w2[k * 64 + tid], o);
    out[b * 64 + tid] = o;
  }
}

extern "C" void kernel_launch(void* const* d_in, const int* in_sizes, int n_in,
                              void* d_out, int out_size, void* d_ws, size_t ws_size,
                              hipStream_t stream) {
  const float* x       = (const float*)d_in[0];
  const float* net_w   = (const float*)d_in[1];
  const float* net_b   = (const float*)d_in[2];
  const float* dwa_w   = (const float*)d_in[3];
  const float* dwa_b   = (const float*)d_in[4];
  const float* pwa_w   = (const float*)d_in[5];
  const float* pwa_b   = (const float*)d_in[6];
  const float* gna_g   = (const float*)d_in[7];
  const float* gna_b   = (const float*)d_in[8];
  const float* dwb_w   = (const float*)d_in[9];
  const float* dwb_b   = (const float*)d_in[10];
  const float* pwb_w   = (const float*)d_in[11];
  const float* pwb_b   = (const float*)d_in[12];
  const float* gnb_g   = (const float*)d_in[13];
  const float* gnb_b   = (const float*)d_in[14];
  const float* dwc_w   = (const float*)d_in[15];
  const float* dwc_b   = (const float*)d_in[16];
  const float* pwc_w   = (const float*)d_in[17];
  const float* pwc_b   = (const float*)d_in[18];
  const float* gnc_g   = (const float*)d_in[19];
  const float* gnc_b   = (const float*)d_in[20];
  const float* merge_w = (const float*)d_in[21];
  const float* merge_b = (const float*)d_in[22];
  const float* mlng    = (const float*)d_in[23];
  const float* mlnb    = (const float*)d_in[24];
  const float* qproj_w = (const float*)d_in[25];
  const float* qproj_b = (const float*)d_in[26];
  const float* poly    = (const float*)d_in[27];
  const float* qff     = (const float*)d_in[28];
  const float* mix_re  = (const float*)d_in[29];
  const float* mix_im  = (const float*)d_in[30];
  const float* qout_w  = (const float*)d_in[31];
  const float* qout_b  = (const float*)d_in[32];
  const float* fc_w    = (const float*)d_in[33];
  const float* fc_b    = (const float*)d_in[34];
  const float* fus1_w  = (const float*)d_in[35];
  const float* fus1_b  = (const float*)d_in[36];
  const float* flng    = (const float*)d_in[37];
  const float* flnb    = (const float*)d_in[38];
  const float* fus2_w  = (const float*)d_in[39];
  const float* fus2_b  = (const float*)d_in[40];
  float* out = (float*)d_out;

  // workspace layout (floats):
  //  [0, 3*SZF)        y1a/y1b/y1c   (dead after k_pw); cat aliases exactly
  //  [3*SZF, 6*SZF)    y2a/y2b/y2c   (dead after k_gn)
  //  acc aliases [0, 2,973,696) — written by k_quantum after k_merge read cat
  //  [6*SZF ...)       angG, fused (fused written once by k_emdw corr blocks)
  float* W = (float*)d_ws;
  float* y1b_  = W;                                // 3*SZF
  float* cat   = W;                                // alias
  float* y2b_  = W + 3 * (size_t)SZF;
  float* acc   = W;                                // alias, len 2,973,696
  float2* angG = (float2*)(W + 6 * (size_t)SZF);   // 371,712 float2
  float* fused = W + 6 * (size_t)SZF + 743424;     // 3,072

  k_emdw<<<dim3(NB, 13), 256, 0, stream>>>(x, net_w, net_b,
      dwa_w, dwa_b, dwb_w, dwb_b, dwc_w, dwc_b, y1b_, fc_w, fc_b, fused);
  k_pw<<<dim3(NB, 6, 3), 256, 0, stream>>>(y1b_, pwa_w, pwb_w, pwc_w, pwa_b, pwb_b, pwc_b, y2b_);
  k_gn<<<dim3(NB, 6, 3), 256, 0, stream>>>(y2b_,
      gna_g, gnb_g, gnc_g, gna_b, gnb_b, gnc_b, cat);
  k_merge<<<726, 256, 0, stream>>>(cat, merge_w, merge_b, mlng, mlnb,
      qproj_w, qproj_b, angG);
  k_quantum<<<NROW / 4, 64, 0, stream>>>(angG, poly, acc);
  k_tail<<<NB, 256, 0, stream>>>(acc, mix_re, mix_im, qff, qout_w, qout_b, fused,
                                 fus1_w, fus1_b, flng, flnb, fus2_w, fus2_b, out);
}

// Round 10
// 313.908 us; speedup vs baseline: 1.7166x; 1.1640x over previous
//
#include <hip/hip_runtime.h>
#include <math.h>

#define NB 16
#define NT 363
#define NC 180
#define SZF 557568   // NB*96*NT
#define NROW 5808    // NB*NT

__device__ __forceinline__ float gelu_f(float x) {
  return 0.5f * x * (1.0f + erff(x * 0.7071067811865475244f));
}

// ================= quantum gate primitives (v2 layout — measured best) =================
// k_quantum: 16 amps/lane. local j = state bits [3:0];
// lane bits [3:0] = state bits [7:4]; lane bits [5:4] = row-in-wave g.
// wire w acts on state bit p = 7-w.
// p<=3 local; p=4 lane^1 (DPP); p=5 lane^2 (DPP); p=6 lane^4 (DS); p=7 lane^8 (DS).

template<int CTRL>
__device__ __forceinline__ float dppf(float x) {
  return __int_as_float(__builtin_amdgcn_update_dpp(
      0, __float_as_int(x), CTRL, 0xF, 0xF, true));
}

template<int LB>
__device__ __forceinline__ float lx(float x) {
  if constexpr (LB == 0) return dppf<0xB1>(x);        // quad_perm xor 1
  else if constexpr (LB == 1) return dppf<0x4E>(x);   // quad_perm xor 2
  else if constexpr (LB == 2) return __shfl_xor(x, 4);
  else return __shfl_xor(x, 8);
}

template<int P>
__device__ __forceinline__ void ry_local(float* re, float* im, float c, float s) {
#pragma unroll
  for (int j = 0; j < 16; ++j) {
    if ((j & (1 << P)) == 0) {
      int k = j | (1 << P);
      float r0 = re[j], i0 = im[j], r1 = re[k], i1 = im[k];
      re[j] = fmaf(c, r0, -s * r1); im[j] = fmaf(c, i0, -s * i1);
      re[k] = fmaf(s, r0,  c * r1); im[k] = fmaf(s, i0,  c * i1);
    }
  }
}

template<int LB>
__device__ __forceinline__ void ry_lane(float* re, float* im, float c, float s, int lane) {
  float sg = (lane & (1 << LB)) ? s : -s;
#pragma unroll
  for (int j = 0; j < 16; ++j) {
    float br = lx<LB>(re[j]);
    float bi = lx<LB>(im[j]);
    re[j] = fmaf(c, re[j], sg * br);
    im[j] = fmaf(c, im[j], sg * bi);
  }
}

template<int Q, int P>  // control local bit Q, target local bit P
__device__ __forceinline__ void crx_ll(float* re, float* im, float cs, float sn) {
#pragma unroll
  for (int j = 0; j < 16; ++j) {
    if ((j & (1 << Q)) && !(j & (1 << P))) {
      int k = j | (1 << P);
      float r0 = re[j], i0 = im[j], r1 = re[k], i1 = im[k];
      re[j] = fmaf(cs, r0,  sn * i1); im[j] = fmaf(cs, i0, -sn * r1);
      re[k] = fmaf(cs, r1,  sn * i0); im[k] = fmaf(cs, i1, -sn * r0);
    }
  }
}

template<int LBQ, int P>  // control lane bit LBQ, target local bit P
__device__ __forceinline__ void crx_nl(float* re, float* im, float cs, float sn, int lane) {
  if (lane & (1 << LBQ)) {
#pragma unroll
    for (int j = 0; j < 16; ++j) {
      if ((j & (1 << P)) == 0) {
        int k = j | (1 << P);
        float r0 = re[j], i0 = im[j], r1 = re[k], i1 = im[k];
        re[j] = fmaf(cs, r0,  sn * i1); im[j] = fmaf(cs, i0, -sn * r1);
        re[k] = fmaf(cs, r1,  sn * i0); im[k] = fmaf(cs, i1, -sn * r0);
      }
    }
  }
}

template<int Q, int LBP>  // control local bit Q, target lane bit LBP
__device__ __forceinline__ void crx_ln(float* re, float* im, float cs, float sn) {
#pragma unroll
  for (int j = 0; j < 16; ++j) {
    if (j & (1 << Q)) {
      float br = lx<LBP>(re[j]);
      float bi = lx<LBP>(im[j]);
      re[j] = fmaf(cs, re[j],  sn * bi);
      im[j] = fmaf(cs, im[j], -sn * br);
    }
  }
}

template<int LBQ, int LBP>  // control lane bit LBQ, target lane bit LBP
__device__ __forceinline__ void crx_nn(float* re, float* im, float cs, float sn, int lane) {
  bool ctl = (lane & (1 << LBQ)) != 0;
#pragma unroll
  for (int j = 0; j < 16; ++j) {
    float br = lx<LBP>(re[j]);
    float bi = lx<LBP>(im[j]);
    if (ctl) {
      re[j] = fmaf(cs, re[j],  sn * bi);
      im[j] = fmaf(cs, im[j], -sn * br);
    }
  }
}

// one reference "layer" = RY ring, CRX(q,q+1) ring, RY ring, CRX(q,q-1) ring
__device__ __forceinline__ void qlayer(float* re, float* im,
                                       const float2* ang, int lane) {
  float2 a;
  a = ang[0];  ry_lane<3>(re, im, a.x, a.y, lane);
  a = ang[1];  ry_lane<2>(re, im, a.x, a.y, lane);
  a = ang[2];  ry_lane<1>(re, im, a.x, a.y, lane);
  a = ang[3];  ry_lane<0>(re, im, a.x, a.y, lane);
  a = ang[4];  ry_local<3>(re, im, a.x, a.y);
  a = ang[5];  ry_local<2>(re, im, a.x, a.y);
  a = ang[6];  ry_local<1>(re, im, a.x, a.y);
  a = ang[7];  ry_local<0>(re, im, a.x, a.y);
  a = ang[8];  crx_nn<3, 2>(re, im, a.x, a.y, lane);
  a = ang[9];  crx_nn<2, 1>(re, im, a.x, a.y, lane);
  a = ang[10]; crx_nn<1, 0>(re, im, a.x, a.y, lane);
  a = ang[11]; crx_nl<0, 3>(re, im, a.x, a.y, lane);
  a = ang[12]; crx_ll<3, 2>(re, im, a.x, a.y);
  a = ang[13]; crx_ll<2, 1>(re, im, a.x, a.y);
  a = ang[14]; crx_ll<1, 0>(re, im, a.x, a.y);
  a = ang[15]; crx_ln<0, 3>(re, im, a.x, a.y);
  a = ang[16]; ry_lane<3>(re, im, a.x, a.y, lane);
  a = ang[17]; ry_lane<2>(re, im, a.x, a.y, lane);
  a = ang[18]; ry_lane<1>(re, im, a.x, a.y, lane);
  a = ang[19]; ry_lane<0>(re, im, a.x, a.y, lane);
  a = ang[20]; ry_local<3>(re, im, a.x, a.y);
  a = ang[21]; ry_local<2>(re, im, a.x, a.y);
  a = ang[22]; ry_local<1>(re, im, a.x, a.y);
  a = ang[23]; ry_local<0>(re, im, a.x, a.y);
  a = ang[24]; crx_nl<3, 0>(re, im, a.x, a.y, lane);
  a = ang[25]; crx_nn<2, 3>(re, im, a.x, a.y, lane);
  a = ang[26]; crx_nn<1, 2>(re, im, a.x, a.y, lane);
  a = ang[27]; crx_nn<0, 1>(re, im, a.x, a.y, lane);
  a = ang[28]; crx_ln<3, 0>(re, im, a.x, a.y);
  a = ang[29]; crx_ll<2, 3>(re, im, a.x, a.y);
  a = ang[30]; crx_ll<1, 2>(re, im, a.x, a.y);
  a = ang[31]; crx_ll<0, 1>(re, im, a.x, a.y);
}

// --- v1 layout helpers (4 amps/lane) for the tail qff step ---
template<int P>
__device__ __forceinline__ void ryg(float* re, float* im, float c, float s, int lane) {
  if constexpr (P >= 2) {
    constexpr int mask = 1 << (P - 2);
    float sg = ((lane >> (P - 2)) & 1) ? s : -s;
#pragma unroll
    for (int j = 0; j < 4; ++j) {
      float br = __shfl_xor(re[j], mask);
      float bi = __shfl_xor(im[j], mask);
      re[j] = fmaf(c, re[j], sg * br);
      im[j] = fmaf(c, im[j], sg * bi);
    }
  } else {
#pragma unroll
    for (int k = 0; k < 2; ++k) {
      const int a = (P == 0) ? 2 * k : k;
      const int b = (P == 0) ? a + 1 : a + 2;
      float r0 = re[a], i0 = im[a], r1 = re[b], i1 = im[b];
      re[a] = fmaf(c, r0, -s * r1); im[a] = fmaf(c, i0, -s * i1);
      re[b] = fmaf(s, r0,  c * r1); im[b] = fmaf(s, i0,  c * i1);
    }
  }
}

template<int PC, int PT>
__device__ __forceinline__ void crxg(float* re, float* im, float cs, float sn, int lane) {
  if constexpr (PT >= 2) {
    constexpr int mask = 1 << (PT - 2);
#pragma unroll
    for (int j = 0; j < 4; ++j) {
      float br = __shfl_xor(re[j], mask);
      float bi = __shfl_xor(im[j], mask);
      bool ctrl;
      if constexpr (PC >= 2) ctrl = ((lane >> (PC - 2)) & 1) != 0;
      else                   ctrl = ((j >> PC) & 1) != 0;
      if (ctrl) {
        float nr = fmaf(cs, re[j],  sn * bi);
        float ni = fmaf(cs, im[j], -sn * br);
        re[j] = nr; im[j] = ni;
      }
    }
  } else {
#pragma unroll
    for (int k = 0; k < 2; ++k) {
      const int a = (PT == 0) ? 2 * k : k;
      const int b = (PT == 0) ? a + 1 : a + 2;
      bool ctrl;
      if constexpr (PC >= 2) ctrl = ((lane >> (PC - 2)) & 1) != 0;
      else                   ctrl = ((a >> PC) & 1) != 0;
      if (ctrl) {
        float r0 = re[a], i0 = im[a], r1 = re[b], i1 = im[b];
        re[a] = fmaf(cs, r0,  sn * i1); im[a] = fmaf(cs, i0, -sn * r1);
        re[b] = fmaf(cs, r1,  sn * i0); im[b] = fmaf(cs, i1, -sn * r0);
      }
    }
  }
}

__device__ __forceinline__ void sim14_layer(float* re, float* im,
                                            const float* Cr, const float* Sr, int lane) {
#define ARY1(q, pi) ryg<7-(q)>(re, im, Cr[pi], Sr[pi], lane)
#define ACX1(cq, tq, pi) crxg<7-(cq), 7-(tq)>(re, im, Cr[pi], Sr[pi], lane)
  ARY1(0,0); ARY1(1,1); ARY1(2,2); ARY1(3,3); ARY1(4,4); ARY1(5,5); ARY1(6,6); ARY1(7,7);
  ACX1(0,1,8); ACX1(1,2,9); ACX1(2,3,10); ACX1(3,4,11); ACX1(4,5,12); ACX1(5,6,13); ACX1(6,7,14); ACX1(7,0,15);
  ARY1(0,16); ARY1(1,17); ARY1(2,18); ARY1(3,19); ARY1(4,20); ARY1(5,21); ARY1(6,22); ARY1(7,23);
  ACX1(0,7,24); ACX1(1,0,25); ACX1(2,1,26); ACX1(3,2,27); ACX1(4,3,28); ACX1(5,4,29); ACX1(6,5,30); ACX1(7,6,31);
#undef ARY1
#undef ACX1
}

// ---------------- K1: fused embed + depthwise conv (blocks y<12) + corr (y==12) ----------------
struct CorrSM { float mu[180]; float inv[180]; float S[NT * 12]; float fcv[78]; };
struct EmdwSM {
  float xs[NT * 15];
  float nwL[120], nbL[8];
  float hrow[8][368];
  float wL[3][8][8];
  float bL[3][8];
};
union EDSM { EmdwSM e; CorrSM c; };

__global__ __launch_bounds__(256) void k_emdw(const float* __restrict__ x,
    const float* __restrict__ nw, const float* __restrict__ nb,
    const float* __restrict__ wa, const float* __restrict__ ba,
    const float* __restrict__ wb, const float* __restrict__ bb,
    const float* __restrict__ wc, const float* __restrict__ bc,
    float* __restrict__ y1base,
    const float* __restrict__ fcw, const float* __restrict__ fcb,
    float* __restrict__ fusedG) {
  __shared__ EDSM sm;
  int b = blockIdx.x, kg = blockIdx.y, tid = threadIdx.x;
  if (kg < 12) {
    for (int i = tid; i < 120; i += 256) sm.e.nwL[i] = nw[kg * 120 + i];
    for (int i = tid; i < 8; i += 256) sm.e.nbL[i] = nb[kg * 8 + i];
    for (int i = tid; i < 168; i += 256) {
      int z = i / 56, r = i % 56, d = r / 7, k = r % 7;
      const float* w = (z == 0) ? wa : ((z == 1) ? wb : wc);
      sm.e.wL[z][d][k] = w[(kg * 8 + d) * 7 + k];
    }
    for (int i = tid; i < 24; i += 256) {
      int z = i / 8, d = i % 8;
      const float* bias = (z == 0) ? ba : ((z == 1) ? bb : bc);
      sm.e.bL[z][d] = bias[kg * 8 + d];
    }
    for (int i = tid; i < NT * 15; i += 256) {
      int t = i / 15, u = i % 15;
      sm.e.xs[i] = x[((size_t)b * NT + t) * NC + kg * 15 + u];
    }
    __syncthreads();
    for (int i = tid; i < 8 * NT; i += 256) {
      int t = i % NT, d = i / NT;
      float acc2 = sm.e.nbL[d];
#pragma unroll
      for (int u = 0; u < 15; ++u) acc2 = fmaf(sm.e.xs[t * 15 + u], sm.e.nwL[u * 8 + d], acc2);
      sm.e.hrow[d][t] = gelu_f(acc2);
    }
    __syncthreads();
    for (int i = tid; i < 8 * NT; i += 256) {
      int t = i % NT, d = i / NT;
      int c = kg * 8 + d;
      float a0 = sm.e.bL[0][d], a1 = sm.e.bL[1][d], a2 = sm.e.bL[2][d];
#pragma unroll
      for (int k = 0; k < 7; ++k) {
        int i1 = t + (k - 3);
        int i4 = t + (k - 3) * 4;
        int i16 = t + (k - 3) * 16;
        if (i1 >= 0 && i1 < NT)  a0 = fmaf(sm.e.hrow[d][i1],  sm.e.wL[0][d][k], a0);
        if (i4 >= 0 && i4 < NT)  a1 = fmaf(sm.e.hrow[d][i4],  sm.e.wL[1][d][k], a1);
        if (i16 >= 0 && i16 < NT) a2 = fmaf(sm.e.hrow[d][i16], sm.e.wL[2][d][k], a2);
      }
      size_t base = ((size_t)b * 96 + c) * NT + t;
      y1base[base] = a0;
      y1base[SZF + base] = a1;
      y1base[2 * SZF + base] = a2;
    }
  } else {
    if (tid < 180) {
      float s = 0;
      const float* px = x + (size_t)b * NT * NC + tid;
      for (int t = 0; t < NT; ++t) s += px[t * NC];
      float mu = s / 363.0f;
      float q = 0;
      for (int t = 0; t < NT; ++t) { float d = px[t * NC] - mu; q = fmaf(d, d, q); }
      float sd = sqrtf(q / 362.0f);
      sd = fmaxf(sd, 1e-8f);
      sm.c.mu[tid] = mu; sm.c.inv[tid] = 1.0f / sd;
    }
    __syncthreads();
    for (int t = tid; t < NT; t += 256) {
      const float* px = x + (size_t)(b * NT + t) * NC;
#pragma unroll
      for (int i = 0; i < 12; ++i) {
        float s = 0;
#pragma unroll
        for (int u = 0; u < 15; ++u) {
          int cidx = i * 15 + u;
          s += (px[cidx] - sm.c.mu[cidx]) * sm.c.inv[cidx];
        }
        sm.c.S[t * 12 + i] = s;
      }
    }
    __syncthreads();
    if (tid < 78) {
      int i = 0, rem = tid;
      while (rem >= 12 - i) { rem -= 12 - i; ++i; }
      int j = i + rem;
      float acc = 0;
      for (int t = 0; t < NT; ++t) acc = fmaf(sm.c.S[t * 12 + i], sm.c.S[t * 12 + j], acc);
      sm.c.fcv[tid] = acc * (1.0f / (225.0f * 362.0f));
    }
    __syncthreads();
    if (tid < 64) {
      float v = fcb[tid];
#pragma unroll
      for (int k = 0; k < 78; ++k) v = fmaf(sm.c.fcv[k], fcw[k * 64 + tid], v);
      fusedG[b * 192 + 128 + tid] = gelu_f(v);
    }
  }
}

// ---------------- K2: pointwise 96x96, branch-batched (R6 version — measured good) ----------------
__global__ __launch_bounds__(256) void k_pw(const float* __restrict__ y1base,
    const float* __restrict__ wA, const float* __restrict__ wB, const float* __restrict__ wC,
    const float* __restrict__ bA, const float* __restrict__ bB, const float* __restrict__ bC,
    float* __restrict__ y2base) {
  int b = blockIdx.x, tile = blockIdx.y, z = blockIdx.z, tid = threadIdx.x;
  const float* pw_w = (z == 0) ? wA : ((z == 1) ? wB : wC);
  const float* pw_b = (z == 0) ? bA : ((z == 1) ? bB : bC);
  const float* y1 = y1base + (size_t)z * SZF;
  float* y2 = y2base + (size_t)z * SZF;
  int t0 = tile * 64;
  __shared__ float y1t[96 * 64];
  __shared__ float pwL[96 * 97];  // pad 97 to break 96-stride bank aliasing
  for (int i = tid; i < 96 * 96; i += 256) {
    int o = i / 96, cc = i % 96;
    pwL[o * 97 + cc] = pw_w[i];
  }
  for (int i = tid; i < 96 * 64; i += 256) {
    int cc = i >> 6, t = i & 63;
    int tt = t0 + t;
    y1t[i] = (tt < NT) ? y1[(b * 96 + cc) * NT + tt] : 0.0f;
  }
  __syncthreads();
  int o16 = tid >> 4, t4 = (tid & 15) * 4;
  for (int pass = 0; pass < 6; ++pass) {
    int o = pass * 16 + o16;
    float bias = pw_b[o];
    float a0 = bias, a1 = bias, a2 = bias, a3 = bias;
    const float* wrow = &pwL[o * 97];
#pragma unroll 4
    for (int cc = 0; cc < 96; ++cc) {
      const float4 vy = *reinterpret_cast<const float4*>(&y1t[cc * 64 + t4]);
      float w = wrow[cc];
      a0 = fmaf(w, vy.x, a0); a1 = fmaf(w, vy.y, a1);
      a2 = fmaf(w, vy.z, a2); a3 = fmaf(w, vy.w, a3);
    }
    int base = (b * 96 + o) * NT;
    int t = t0 + t4;
    if (t + 3 < NT) {
      y2[base + t] = a0; y2[base + t + 1] = a1; y2[base + t + 2] = a2; y2[base + t + 3] = a3;
    } else {
      if (t < NT) y2[base + t] = a0;
      if (t + 1 < NT) y2[base + t + 1] = a1;
      if (t + 2 < NT) y2[base + t + 2] = a2;
      if (t + 3 < NT) y2[base + t + 3] = a3;
    }
  }
}

// ---------------- K3: groupnorm stats (two-pass, R6 measured) ----------------
__global__ __launch_bounds__(256) void k_gnstat(const float* __restrict__ y2base,
                                                float* __restrict__ muG,
                                                float* __restrict__ rsG) {
  int b = blockIdx.x, g = blockIdx.y, z = blockIdx.z, tid = threadIdx.x;
  __shared__ float red[256];
  const float* base = y2base + (size_t)z * SZF + (b * 96 + g * 12) * NT;
  float s = 0;
  for (int i = tid; i < 12 * NT; i += 256) s += base[i];
  red[tid] = s; __syncthreads();
  for (int st = 128; st > 0; st >>= 1) { if (tid < st) red[tid] += red[tid + st]; __syncthreads(); }
  float mu = red[0] / 4356.0f;
  __syncthreads();
  float q = 0;
  for (int i = tid; i < 12 * NT; i += 256) { float d = base[i] - mu; q = fmaf(d, d, q); }
  red[tid] = q; __syncthreads();
  for (int st = 128; st > 0; st >>= 1) { if (tid < st) red[tid] += red[tid + st]; __syncthreads(); }
  if (tid == 0) {
    float var = red[0] / 4356.0f;
    muG[(z * NB + b) * 8 + g] = mu;
    rsG[(z * NB + b) * 8 + g] = rsqrtf(var + 1e-5f);
  }
}

// ---------------- K4: groupnorm apply + gelu -> cat (R6 measured) ----------------
__global__ __launch_bounds__(256) void k_gnapply(const float* __restrict__ y2base,
    const float* __restrict__ muG, const float* __restrict__ rsG,
    const float* __restrict__ gA, const float* __restrict__ gB, const float* __restrict__ gC,
    const float* __restrict__ bA, const float* __restrict__ bB, const float* __restrict__ bC,
    float* __restrict__ cat) {
  int b = blockIdx.x, tile = blockIdx.y, z = blockIdx.z, tid = threadIdx.x;
  const float* gng = (z == 0) ? gA : ((z == 1) ? gB : gC);
  const float* gnb = (z == 0) ? bA : ((z == 1) ? bB : bC);
  const float* y2 = y2base + (size_t)z * SZF;
  int t0 = tile * 64;
  __shared__ float yL[96 * 65];
  __shared__ float muL[8], rsL[8];
  if (tid < 8) { muL[tid] = muG[(z * NB + b) * 8 + tid]; rsL[tid] = rsG[(z * NB + b) * 8 + tid]; }
  for (int i = tid; i < 96 * 64; i += 256) {
    int cc = i >> 6, t = i & 63;
    int tt = t0 + t;
    yL[cc * 65 + t] = (tt < NT) ? y2[(b * 96 + cc) * NT + tt] : 0.0f;
  }
  __syncthreads();
  for (int i = tid; i < 64 * 96; i += 256) {
    int tt = i / 96, cc = i % 96;
    int t = t0 + tt;
    if (t < NT) {
      int g = cc / 12;
      float v = (yL[cc * 65 + tt] - muL[g]) * rsL[g] * gng[cc] + gnb[cc];
      cat[((size_t)b * NT + t) * 288 + z * 96 + cc] = gelu_f(v);
    }
  }
}

// ---------------- K5: merge GEMM + LN + GELU + qproj + sigmoid (scalar, R4-proven) ----------------
__global__ __launch_bounds__(256) void k_merge(const float* __restrict__ cat,
    const float* __restrict__ mw, const float* __restrict__ mb,
    const float* __restrict__ lng, const float* __restrict__ lnb,
    const float* __restrict__ qw, const float* __restrict__ qb,
    float2* __restrict__ angG) {
  int blk = blockIdx.x, tid = threadIdx.x;
  __shared__ float catL[8][288];
  __shared__ float vL[8][129];
  __shared__ float hL[8][129];
  __shared__ float muS[8], rsS[8];
  for (int i = tid; i < 8 * 288; i += 256) {
    int r = i / 288, k = i % 288;
    catL[r][k] = cat[((size_t)blk * 8 + r) * 288 + k];
  }
  __syncthreads();
  int jj = tid & 127, rg = tid >> 7;
  float bias = mb[jj];
  float acc[4] = {bias, bias, bias, bias};
  for (int k = 0; k < 288; ++k) {
    float w = mw[k * 128 + jj];
#pragma unroll
    for (int r = 0; r < 4; ++r) acc[r] = fmaf(catL[rg * 4 + r][k], w, acc[r]);
  }
#pragma unroll
  for (int r = 0; r < 4; ++r) vL[rg * 4 + r][jj] = acc[r];
  __syncthreads();
  if (tid < 8) {
    float s = 0;
    for (int k = 0; k < 128; ++k) s += vL[tid][k];
    float mu = s / 128.0f;
    float q = 0;
    for (int k = 0; k < 128; ++k) { float d = vL[tid][k] - mu; q = fmaf(d, d, q); }
    muS[tid] = mu;
    rsS[tid] = rsqrtf(q / 128.0f + 1e-5f);
  }
  __syncthreads();
  float g = lng[jj], bb2 = lnb[jj];
#pragma unroll
  for (int r = 0; r < 4; ++r) {
    int row = rg * 4 + r;
    float h = (acc[r] - muS[row]) * rsS[row] * g + bb2;
    hL[row][jj] = gelu_f(h);
  }
  __syncthreads();
  int o = tid & 63;
  int r0 = (tid >> 6) * 2;
  for (int rr = 0; rr < 2; ++rr) {
    int row = r0 + rr;
    float u = qb[o];
    for (int k = 0; k < 128; ++k) u = fmaf(hL[row][k], qw[k * 64 + o], u);
    float tp = 6.2831853071795864769f / (1.0f + expf(-u));
    float hf = tp * 0.5f;
    int grow = blk * 8 + row;
    angG[(size_t)grow * 64 + o] = make_float2(cosf(hf), sinf(hf));
  }
}

// ---------------- K6: quantum ansatz (v2: 16 amps/lane, 4 rows/wave, Horner) ----------------
__global__ __launch_bounds__(64) void k_quantum(const float2* __restrict__ angG,
                                                const float* __restrict__ pc4,
                                                float* __restrict__ accG) {
  const int lane = threadIdx.x;
  const int g = lane >> 4;
  const int ll = lane & 15;
  const int row0 = blockIdx.x * 4;
  __shared__ float2 angL[4][66];  // pad 66 so the 4 subgroup bases hit distinct banks
#pragma unroll
  for (int q = 0; q < 4; ++q)
    angL[q][lane] = angG[(size_t)(row0 + q) * 64 + lane];
  __syncthreads();
  float p0 = pc4[0], p1 = pc4[1], p2 = pc4[2], p3 = pc4[3];
  float re[16], im[16];
#pragma unroll
  for (int j = 0; j < 16; ++j) { re[j] = 0.0f; im[j] = 0.0f; }
  // Horner: acc = p0 + U(p1 + U(p2 + U*p3)) |0>
  if (ll == 0) re[0] = p3;
  const float2* ang = &angL[g][0];
  for (int rep = 0; rep < 3; ++rep) {
    qlayer(re, im, ang, lane);
    qlayer(re, im, ang + 32, lane);
    float pc = (rep == 0) ? p2 : (rep == 1) ? p1 : p0;
    if (ll == 0) re[0] += pc;
  }
  int row = row0 + g;
  float4* dst = reinterpret_cast<float4*>(accG + ((size_t)row * 256 + ll * 16) * 2);
#pragma unroll
  for (int h = 0; h < 8; ++h)
    dst[h] = make_float4(re[2 * h], im[2 * h], re[2 * h + 1], im[2 * h + 1]);
}

// ---------------- K7: mix partial reduce over T (11 chunks of 33) ----------------
__global__ __launch_bounds__(256) void k_mix1(const float* __restrict__ accG,
                                              const float* __restrict__ mr,
                                              const float* __restrict__ mi,
                                              float* __restrict__ part) {
  int b = blockIdx.x, ch = blockIdx.y, d = threadIdx.x;
  int t0 = ch * 33;
  float sr = 0, si = 0;
  for (int i = 0; i < 33; ++i) {
    int t = t0 + i;
    const float2 a = *reinterpret_cast<const float2*>(accG + (size_t)((b * NT + t) * 256 + d) * 2);
    float m_r = mr[t], m_i = mi[t];
    sr = fmaf(m_r, a.x, fmaf(-m_i, a.y, sr));
    si = fmaf(m_r, a.y, fmaf(m_i, a.x, si));
  }
  float2* o = reinterpret_cast<float2*>(part + (size_t)((b * 11 + ch) * 256 + d) * 2);
  *o = make_float2(sr, si);
}

// ---------------- K8: tail — mix-final + qff + pauli + qout + final MLP -> out ----------------
__global__ __launch_bounds__(256) void k_tail(const float* __restrict__ part,
    const float* __restrict__ qff,
    const float* __restrict__ qout_w, const float* __restrict__ qout_b,
    const float* __restrict__ fusedG,
    const float* __restrict__ w1, const float* __restrict__ b1,
    const float* __restrict__ lng, const float* __restrict__ lnb,
    const float* __restrict__ w2, const float* __restrict__ b2,
    float* __restrict__ out) {
  int b = blockIdx.x, tid = threadIdx.x;
  __shared__ float psiL[256][2];
  __shared__ float red[256];
  __shared__ float qcL[32], qsL[32], exps[24];
  __shared__ float tL[128], cL[64], hL[128];
  {
    float sr = 0, si = 0;
    for (int ch = 0; ch < 11; ++ch) {
      const float2 a = *reinterpret_cast<const float2*>(part + (size_t)((b * 11 + ch) * 256 + tid) * 2);
      sr += a.x; si += a.y;
    }
    psiL[tid][0] = sr; psiL[tid][1] = si;
    red[tid] = sr * sr + si * si;
  }
  if (tid < 32) { float h = qff[tid] * 0.5f; qcL[tid] = cosf(h); qsL[tid] = sinf(h); }
  __syncthreads();
  for (int s2 = 128; s2 > 0; s2 >>= 1) { if (tid < s2) red[tid] += red[tid + s2]; __syncthreads(); }
  float inv = 1.0f / (sqrtf(red[0]) + 1e-9f);
  __syncthreads();
  if (tid < 64) {
    int lane = tid;
    float re[4], im[4];
#pragma unroll
    for (int j = 0; j < 4; ++j) {
      re[j] = psiL[lane * 4 + j][0] * inv;
      im[j] = psiL[lane * 4 + j][1] * inv;
    }
    sim14_layer(re, im, qcL, qsL, lane);
#pragma unroll
    for (int j = 0; j < 4; ++j) { psiL[lane * 4 + j][0] = re[j]; psiL[lane * 4 + j][1] = im[j]; }
  }
  __syncthreads();
  if (tid < 64) {
    int lane = tid;
    for (int w = 0; w < 8; ++w) {
      int p = 7 - w;
      float cr = 0, ci = 0, z = 0;
#pragma unroll
      for (int k = 0; k < 2; ++k) {
        int pr = lane + k * 64;
        int lowmask = (1 << p) - 1;
        int i0 = ((pr >> p) << (p + 1)) | (pr & lowmask);
        int i1 = i0 | (1 << p);
        float r0 = psiL[i0][0], I0 = psiL[i0][1], r1 = psiL[i1][0], I1 = psiL[i1][1];
        cr += r0 * r1 + I0 * I1;
        ci += r0 * I1 - I0 * r1;
        z += r0 * r0 + I0 * I0 - r1 * r1 - I1 * I1;
      }
      for (int off = 32; off > 0; off >>= 1) {
        cr += __shfl_down(cr, off);
        ci += __shfl_down(ci, off);
        z  += __shfl_down(z, off);
      }
      if (lane == 0) { exps[w] = 2.0f * cr; exps[8 + w] = 2.0f * ci; exps[16 + w] = z; }
    }
  }
  __syncthreads();
  if (tid < 128) {
    float v = qout_b[tid];
#pragma unroll
    for (int k = 0; k < 24; ++k) v = fmaf(exps[k], qout_w[k * 128 + tid], v);
    tL[tid] = v;
  } else if (tid < 192) {
    cL[tid - 128] = fusedG[b * 192 + 128 + (tid - 128)];
  }
  __syncthreads();
  float v = 0.0f;
  if (tid < 128) {
    v = b1[tid];
    for (int k = 0; k < 128; ++k) v = fmaf(tL[k], w1[k * 128 + tid], v);
    for (int k = 0; k < 64; ++k)  v = fmaf(cL[k], w1[(128 + k) * 128 + tid], v);
    red[tid] = v;
  }
  __syncthreads();
  for (int s = 64; s > 0; s >>= 1) { if (tid < s) red[tid] += red[tid + s]; __syncthreads(); }
  float mu = red[0] / 128.0f;
  __syncthreads();
  float dv = v - mu;
  if (tid < 128) red[tid] = dv * dv;
  __syncthreads();
  for (int s = 64; s > 0; s >>= 1) { if (tid < s) red[tid] += red[tid + s]; __syncthreads(); }
  float var = red[0] / 128.0f;
  if (tid < 128) hL[tid] = gelu_f(dv * rsqrtf(var + 1e-5f) * lng[tid] + lnb[tid]);
  __syncthreads();
  if (tid < 64) {
    float o = b2[tid];
    for (int k = 0; k < 128; ++k) o = fmaf(hL[k], w2[k * 64 + tid], o);
    out[b * 64 + tid] = o;
  }
}

extern "C" void kernel_launch(void* const* d_in, const int* in_sizes, int n_in,
                              void* d_out, int out_size, void* d_ws, size_t ws_size,
                              hipStream_t stream) {
  const float* x       = (const float*)d_in[0];
  const float* net_w   = (const float*)d_in[1];
  const float* net_b   = (const float*)d_in[2];
  const float* dwa_w   = (const float*)d_in[3];
  const float* dwa_b   = (const float*)d_in[4];
  const float* pwa_w   = (const float*)d_in[5];
  const float* pwa_b   = (const float*)d_in[6];
  const float* gna_g   = (const float*)d_in[7];
  const float* gna_b   = (const float*)d_in[8];
  const float* dwb_w   = (const float*)d_in[9];
  const float* dwb_b   = (const float*)d_in[10];
  const float* pwb_w   = (const float*)d_in[11];
  const float* pwb_b   = (const float*)d_in[12];
  const float* gnb_g   = (const float*)d_in[13];
  const float* gnb_b   = (const float*)d_in[14];
  const float* dwc_w   = (const float*)d_in[15];
  const float* dwc_b   = (const float*)d_in[16];
  const float* pwc_w   = (const float*)d_in[17];
  const float* pwc_b   = (const float*)d_in[18];
  const float* gnc_g   = (const float*)d_in[19];
  const float* gnc_b   = (const float*)d_in[20];
  const float* merge_w = (const float*)d_in[21];
  const float* merge_b = (const float*)d_in[22];
  const float* mlng    = (const float*)d_in[23];
  const float* mlnb    = (const float*)d_in[24];
  const float* qproj_w = (const float*)d_in[25];
  const float* qproj_b = (const float*)d_in[26];
  const float* poly    = (const float*)d_in[27];
  const float* qff     = (const float*)d_in[28];
  const float* mix_re  = (const float*)d_in[29];
  const float* mix_im  = (const float*)d_in[30];
  const float* qout_w  = (const float*)d_in[31];
  const float* qout_b  = (const float*)d_in[32];
  const float* fc_w    = (const float*)d_in[33];
  const float* fc_b    = (const float*)d_in[34];
  const float* fus1_w  = (const float*)d_in[35];
  const float* fus1_b  = (const float*)d_in[36];
  const float* flng    = (const float*)d_in[37];
  const float* flnb    = (const float*)d_in[38];
  const float* fus2_w  = (const float*)d_in[39];
  const float* fus2_b  = (const float*)d_in[40];
  float* out = (float*)d_out;

  // workspace layout (floats):
  //  [0, 3*SZF)        y1a/y1b/y1c   (dead after k_pw); cat aliases exactly
  //  [3*SZF, 6*SZF)    y2a/y2b/y2c   (dead after k_gnapply)
  //  acc aliases [0, 2,973,696) — written by k_quantum after k_merge read cat
  //  [6*SZF ...)       angG, muG, rsG, part, fused
  float* W = (float*)d_ws;
  float* y1b_  = W;                                // 3*SZF
  float* cat   = W;                                // alias
  float* y2b_  = W + 3 * (size_t)SZF;
  float* acc   = W;                                // alias, len 2,973,696
  float2* angG = (float2*)(W + 6 * (size_t)SZF);   // 371,712 float2
  float* muG   = W + 6 * (size_t)SZF + 743424;     // 512
  float* rsG   = muG + 512;                        // 512
  float* part  = rsG + 512;                        // 16*11*256*2 = 90,112
  float* fused = part + 90112;                     // 3,072

  k_emdw<<<dim3(NB, 13), 256, 0, stream>>>(x, net_w, net_b,
      dwa_w, dwa_b, dwb_w, dwb_b, dwc_w, dwc_b, y1b_, fc_w, fc_b, fused);
  k_pw<<<dim3(NB, 6, 3), 256, 0, stream>>>(y1b_, pwa_w, pwb_w, pwc_w, pwa_b, pwb_b, pwc_b, y2b_);
  k_gnstat<<<dim3(NB, 8, 3), 256, 0, stream>>>(y2b_, muG, rsG);
  k_gnapply<<<dim3(NB, 6, 3), 256, 0, stream>>>(y2b_, muG, rsG,
      gna_g, gnb_g, gnc_g, gna_b, gnb_b, gnc_b, cat);
  k_merge<<<726, 256, 0, stream>>>(cat, merge_w, merge_b, mlng, mlnb,
      qproj_w, qproj_b, angG);
  k_quantum<<<NROW / 4, 64, 0, stream>>>(angG, poly, acc);
  k_mix1<<<dim3(NB, 11), 256, 0, stream>>>(acc, mix_re, mix_im, part);
  k_tail<<<NB, 256, 0, stream>>>(part, qff, qout_w, qout_b, fused,
                                 fus1_w, fus1_b, flng, flnb, fus2_w, fus2_b, out);
}